// Round 18
// baseline (18266.438 us; speedup 1.0000x reference)
//
#include <hip/hip_runtime.h>
#include <math.h>

// ---------------------------------------------------------------------------
// FraudGAT: bf16 storage, MFMA projections, pre-transposed bf16 weights.
// R18 = R16 (reg-staged k_mfma with LSTR=72 padding, known good) + R17's
// short8 k_bnp. R17's global_load_lds staging REVERTED: linear [row][64]
// LDS gives a 16-way bank conflict on every ds_read_b128 (row stride 128B
// -> all rows in bank 0), costing ~5.7x on the LDS path (+76% total).
// ---------------------------------------------------------------------------

typedef unsigned short BF16;
typedef short short8 __attribute__((ext_vector_type(8)));
typedef float f32x4 __attribute__((ext_vector_type(4)));
typedef __bf16 bf16x8 __attribute__((ext_vector_type(8)));

static __device__ __forceinline__ float lrelu(float x){ return x > 0.f ? x : 0.2f*x; }

__device__ __forceinline__ float ldE(const float* p, long i){ return p[i]; }
__device__ __forceinline__ float ldE(const BF16* p, long i){
  return __uint_as_float((unsigned)p[i] << 16);
}
__device__ __forceinline__ void stE(float* p, long i, float v){ p[i] = v; }
__device__ __forceinline__ void stE(BF16* p, long i, float v){
  unsigned u = __float_as_uint(v);
  p[i] = (BF16)((u + 0x7FFFu + ((u >> 16) & 1u)) >> 16);
}
__device__ __forceinline__ BF16 f2bf(float v){
  unsigned u = __float_as_uint(v);
  return (BF16)((u + 0x7FFFu + ((u >> 16) & 1u)) >> 16);
}
__device__ __forceinline__ float bf2f(short s){
  return __uint_as_float((unsigned)(unsigned short)s << 16);
}
__device__ __forceinline__ float4 ld4E(const float* p, long i){ return *(const float4*)(p + i); }
__device__ __forceinline__ float4 ld4E(const BF16* p, long i){
  ushort4 s = *(const ushort4*)(p + i);
  return make_float4(__uint_as_float((unsigned)s.x<<16), __uint_as_float((unsigned)s.y<<16),
                     __uint_as_float((unsigned)s.z<<16), __uint_as_float((unsigned)s.w<<16));
}

// ---------------- utility ----------------
__global__ void k_zero(int* __restrict__ p, long n){
  long i = (long)blockIdx.x*blockDim.x + threadIdx.x;
  if (i < n) p[i] = 0;
}
__global__ void k_fill_f32(float* __restrict__ p, long n, float v){
  long i = (long)blockIdx.x*blockDim.x + threadIdx.x;
  if (i < n) p[i] = v;
}

// ---------------- weight transpose+convert (z-batched) --------------------
__global__ __launch_bounds__(256) void k_wt(const float* __restrict__ in, BF16* __restrict__ out,
                                            int K, int N)
{
  in  += (long)blockIdx.z*K*N;
  out += (long)blockIdx.z*N*K;
  __shared__ float t[32][33];
  int kb = blockIdx.y*32, nb = blockIdx.x*32;
  int tx = threadIdx.x & 31, ty8 = threadIdx.x >> 5;
  for (int j = ty8; j < 32; j += 8){
    int k = kb + j, n = nb + tx;
    t[j][tx] = (k < K && n < N) ? in[(long)k*N + n] : 0.f;
  }
  __syncthreads();
  for (int j = ty8; j < 32; j += 8){
    int n = nb + j, k = kb + tx;
    if (n < N && k < K) out[(long)n*K + k] = f2bf(t[tx][j]);
  }
}

// ---------------- fold ALL 12 tables in one launch ------------------------
__global__ __launch_bounds__(256) void k_foldAll(
    const float* __restrict__ Wbase, long wstride,
    const float* __restrict__ atts, const float* __restrict__ attd,
    float* __restrict__ F, int Din)
{
  int w = (blockIdx.x*256 + threadIdx.x) >> 6;
  int lane = threadIdx.x & 63;
  int total = 48*Din;
  if (w >= total) return;
  int k = w % Din;
  int rem = w / Din;
  int h = rem & 3, sd = (rem >> 2) & 1, r = rem >> 3;
  const float* wr = Wbase + (long)r*wstride + (long)k*512 + h*128;
  const float* ar = (sd ? attd : atts) + r*512 + h*128;
  float p = wr[lane]*ar[lane] + wr[lane+64]*ar[lane+64];
  #pragma unroll
  for (int off = 32; off; off >>= 1) p += __shfl_down(p, off, 64);
  if (lane == 0) F[(long)((r*2+sd)*4 + h)*Din + k] = p;
}

// ---------------- MFMA GEMM (reg staging, LSTR=72 pad; optionally z-batched)
template<int BN, int WM, int WN, int FM, int FN, typename TC>
__global__ __launch_bounds__(256) void k_mfma(
    const BF16* __restrict__ A, const BF16* __restrict__ Bt, TC* __restrict__ C,
    int M, int K, int c0, int ldc, int lda, const float* __restrict__ bias,
    int doRelu, int accum, long aZst, long cZst, int c0Zst, const BF16* __restrict__ Bt1)
{
  constexpr int BM = 128;
  constexpr int LSTR = 72;
  __shared__ __attribute__((aligned(16))) short Als[BM][LSTR];
  __shared__ __attribute__((aligned(16))) short Bls[BN][LSTR];
  const int z = blockIdx.z;
  A += (long)z*aZst;
  C += (long)z*cZst;
  c0 += z*c0Zst;
  if (z >= 1 && Bt1) Bt = Bt1;
  const int bn0 = blockIdx.x * BN;
  const int bm = blockIdx.y*BM;
  const int tid = threadIdx.x;
  const int wave = tid >> 6, lane = tid & 63;
  const int wr = wave / WN, wc = wave % WN;
  const int lrow = lane & 15, kg = lane >> 4;
  f32x4 acc[FM][FN] = {};
  for (int k0 = 0; k0 < K; k0 += 64){
    #pragma unroll
    for (int t = 0; t < 4; ++t){
      int idx = tid + t*256;
      int row = idx >> 3, kc = (idx & 7) << 3;
      int gr = bm + row;
      short8 v = {};
      if (gr < M) v = *(const short8*)(A + (long)gr*lda + k0 + kc);
      *(short8*)&Als[row][kc] = v;
    }
    #pragma unroll
    for (int t = 0; t < BN/32; ++t){
      int idx = tid + t*256;
      int row = idx >> 3, kc = (idx & 7) << 3;
      *(short8*)&Bls[row][kc] = *(const short8*)(Bt + (long)(c0+bn0+row)*K + k0 + kc);
    }
    __syncthreads();
    #pragma unroll
    for (int kk = 0; kk < 2; ++kk){
      short8 af[FM], bq[FN];
      #pragma unroll
      for (int m = 0; m < FM; ++m)
        af[m] = *(const short8*)&Als[wr*FM*16 + m*16 + lrow][kk*32 + kg*8];
      #pragma unroll
      for (int n = 0; n < FN; ++n)
        bq[n] = *(const short8*)&Bls[wc*FN*16 + n*16 + lrow][kk*32 + kg*8];
      #pragma unroll
      for (int m = 0; m < FM; ++m)
        #pragma unroll
        for (int n = 0; n < FN; ++n)
          acc[m][n] = __builtin_amdgcn_mfma_f32_16x16x32_bf16(
              __builtin_bit_cast(bf16x8, af[m]), __builtin_bit_cast(bf16x8, bq[n]),
              acc[m][n], 0, 0, 0);
    }
    __syncthreads();
  }
  // epilogue: C/D layout col=lane&15, row=(lane>>4)*4+reg  [m89]
  #pragma unroll
  for (int m = 0; m < FM; ++m){
    #pragma unroll
    for (int n = 0; n < FN; ++n){
      #pragma unroll
      for (int j = 0; j < 4; ++j){
        int row = bm + wr*FM*16 + m*16 + kg*4 + j;
        if (row >= M) continue;
        int col = wc*FN*16 + n*16 + lrow;
        float v = acc[m][n][j];
        if (bias) v += bias[bn0 + col];
        if (doRelu) v = fmaxf(v, 0.f);
        long idx = (long)row*ldc + bn0 + col;
        if (accum) v += ldE(C, idx);
        stE(C, idx, v);
      }
    }
  }
}

// ---------------- naive GEMM (f32 A) for the tiny encoders ----------------
template<typename TA, typename TC>
__global__ __launch_bounds__(256) void k_gemm(
    const TA* __restrict__ A, const float* __restrict__ B, TC* __restrict__ C,
    int M, int N, int K, int ldb, const float* __restrict__ bias, int doRelu)
{
  __shared__ float As[16][64];
  __shared__ float Bs[16][64];
  const int bm = blockIdx.y*64, bn = blockIdx.x*64;
  const int tid = threadIdx.x;
  const int ty = tid >> 4, tx = tid & 15;
  const int ar = tid >> 2;
  const int ac = (tid & 3) << 2;
  const int br = tid >> 4;
  const int bc = (tid & 15) << 2;
  float acc[4][4] = {};
  for (int k0 = 0; k0 < K; k0 += 16){
    int row = bm + ar;
    float4 av = make_float4(0.f,0.f,0.f,0.f);
    if (row < M) av = ld4E(A, (long)row*K + k0 + ac);
    As[ac+0][ar]=av.x; As[ac+1][ar]=av.y; As[ac+2][ar]=av.z; As[ac+3][ar]=av.w;
    float4 bv = make_float4(0.f,0.f,0.f,0.f);
    if (bn + bc + 3 < N) bv = *(const float4*)(B + (long)(k0+br)*ldb + bn + bc);
    *(float4*)&Bs[br][bc] = bv;
    __syncthreads();
    #pragma unroll
    for (int kk = 0; kk < 16; ++kk){
      float a[4], b[4];
      #pragma unroll
      for (int x = 0; x < 4; ++x){ a[x]=As[kk][ty*4+x]; b[x]=Bs[kk][tx*4+x]; }
      #pragma unroll
      for (int y = 0; y < 4; ++y)
        #pragma unroll
        for (int x = 0; x < 4; ++x) acc[y][x] += a[y]*b[x];
    }
    __syncthreads();
  }
  #pragma unroll
  for (int y = 0; y < 4; ++y){
    int row = bm + ty*4 + y;
    if (row >= M) continue;
    #pragma unroll
    for (int x = 0; x < 4; ++x){
      int col = bn + tx*4 + x;
      if (col >= N) continue;
      float v = acc[y][x];
      if (bias) v += bias[col];
      if (doRelu) v = fmaxf(v, 0.f);
      stE(C, (long)row*N + col, v);
    }
  }
}

// ---------------- merged scores: R relations, one pass over X -------------
template<int R>
__global__ __launch_bounds__(256) void k_scoreM(
    const BF16* __restrict__ X, const float* __restrict__ Ftab, long fstride,
    float* __restrict__ out, long ostride, int N, int Din)
{
  int wave = threadIdx.x >> 6, lane = threadIdx.x & 63;
  int node0 = blockIdx.x*16 + wave*4;
  if (node0 >= N) return;
  int base = lane*8;
  bool act = base < Din;
  float x[4][8];
  #pragma unroll
  for (int t = 0; t < 4; ++t){
    int node = node0 + t;
    if (act && node < N){
      short8 v = *(const short8*)(X + (long)node*Din + base);
      #pragma unroll
      for (int j = 0; j < 8; ++j) x[t][j] = bf2f(v[j]);
    } else {
      #pragma unroll
      for (int j = 0; j < 8; ++j) x[t][j] = 0.f;
    }
  }
  #pragma unroll
  for (int r = 0; r < R; ++r){
    const float* F = Ftab + (long)r*fstride;
    float p[4][4] = {};
    #pragma unroll
    for (int h = 0; h < 4; ++h){
      float f[8];
      if (act){
        float4 fa = *(const float4*)(F + h*Din + base);
        float4 fb = *(const float4*)(F + h*Din + base + 4);
        f[0]=fa.x; f[1]=fa.y; f[2]=fa.z; f[3]=fa.w;
        f[4]=fb.x; f[5]=fb.y; f[6]=fb.z; f[7]=fb.w;
      } else {
        #pragma unroll
        for (int j = 0; j < 8; ++j) f[j] = 0.f;
      }
      #pragma unroll
      for (int t = 0; t < 4; ++t)
        #pragma unroll
        for (int j = 0; j < 8; ++j) p[t][h] += x[t][j]*f[j];
    }
    #pragma unroll
    for (int t = 0; t < 4; ++t)
      #pragma unroll
      for (int h = 0; h < 4; ++h)
        #pragma unroll
        for (int off = 32; off; off >>= 1)
          p[t][h] += __shfl_down(p[t][h], off, 64);
    if (lane == 0){
      #pragma unroll
      for (int t = 0; t < 4; ++t){
        int node = node0 + t;
        if (node < N){
          #pragma unroll
          for (int h = 0; h < 4; ++h)
            out[(long)r*ostride + (long)node*4 + h] = p[t][h];
        }
      }
    }
  }
}

// ---------------- CSR build (per-relation) --------------------------------
__global__ void k_hist(const int* __restrict__ dst, int* __restrict__ counts, int E, int nd){
  int e = blockIdx.x*blockDim.x + threadIdx.x;
  if (e >= E) return;
  int d = dst[e];
  if ((unsigned)d < (unsigned)nd) atomicAdd(&counts[d], 1);
}
__global__ void k_scan1(const int* __restrict__ counts, int* __restrict__ indptr,
                        int* __restrict__ bsums, int n)
{
  __shared__ int sm[256];
  int i = blockIdx.x*256 + threadIdx.x;
  int v = (i < n) ? counts[i] : 0;
  sm[threadIdx.x] = v; __syncthreads();
  for (int off = 1; off < 256; off <<= 1){
    int t = (threadIdx.x >= off) ? sm[threadIdx.x - off] : 0;
    __syncthreads();
    sm[threadIdx.x] += t;
    __syncthreads();
  }
  if (i < n) indptr[i+1] = sm[threadIdx.x];
  if (threadIdx.x == 255) bsums[blockIdx.x] = sm[255];
  if (blockIdx.x == 0 && threadIdx.x == 0) indptr[0] = 0;
}
__global__ void k_scan2(int* __restrict__ bsums, int nb){
  __shared__ int sm[1024];
  int t = threadIdx.x;
  int v = (t < nb) ? bsums[t] : 0;
  sm[t] = v; __syncthreads();
  for (int off = 1; off < 1024; off <<= 1){
    int x = (t >= off) ? sm[t - off] : 0;
    __syncthreads();
    sm[t] += x;
    __syncthreads();
  }
  if (t < nb) bsums[t] = sm[t];
}
__global__ void k_scan3(int* __restrict__ indptr, const int* __restrict__ bsums, int n){
  if (blockIdx.x == 0) return;
  int i = blockIdx.x*256 + threadIdx.x;
  int add = bsums[blockIdx.x - 1];
  if (i < n) indptr[i+1] += add;
}
__global__ void k_scatter(const int* __restrict__ src, const int* __restrict__ dst,
                          const int* __restrict__ indptr, int* __restrict__ cursor,
                          int* __restrict__ esrc, int E, int nd, int ns)
{
  int e = blockIdx.x*blockDim.x + threadIdx.x;
  if (e >= E) return;
  int d = dst[e];
  if ((unsigned)d >= (unsigned)nd) return;
  int s = src[e];
  if ((unsigned)s >= (unsigned)ns) s = 0;
  int pos = indptr[d] + atomicAdd(&cursor[d], 1);
  if (pos >= 0 && pos < E) esrc[pos] = s;
}

// ---------------- batched per-edge alpha (3 relations, grid.y) ------------
struct AlphaArgs {
  const float* ss[3]; const float* sd[3];
  const int* ip[3]; const int* es[3];
  float* al[3]; int nd[3]; int ns[3];
};
__global__ __launch_bounds__(256) void k_alpha3b(AlphaArgs a, int E){
  int r = blockIdx.y;
  int wid = (blockIdx.x*blockDim.x + threadIdx.x) >> 6;
  int lane = threadIdx.x & 63;
  if (wid >= a.nd[r]) return;
  const int* indptr = a.ip[r];
  const int* esrc = a.es[r];
  const float* ss = a.ss[r];
  int ns = a.ns[r];
  int e0 = indptr[wid], e1 = indptr[wid+1];
  e0 = max(0, min(e0, E)); e1 = max(e0, min(e1, E));
  if (e0 >= e1) return;
  int h = lane >> 4, g = lane & 15;
  float sdl = a.sd[r][(long)wid*4 + h];
  float* alpha = a.al[r];
  float m = -INFINITY;
  for (int e = e0 + g; e < e1; e += 16){
    int s = esrc[e]; if ((unsigned)s >= (unsigned)ns) s = 0;
    m = fmaxf(m, lrelu(ss[(long)s*4 + h] + sdl));
  }
  #pragma unroll
  for (int o = 1; o < 16; o <<= 1) m = fmaxf(m, __shfl_xor(m, o, 16));
  float den = 0.f;
  for (int e = e0 + g; e < e1; e += 16){
    int s = esrc[e]; if ((unsigned)s >= (unsigned)ns) s = 0;
    den += __expf(lrelu(ss[(long)s*4 + h] + sdl) - m);
  }
  #pragma unroll
  for (int o = 1; o < 16; o <<= 1) den += __shfl_xor(den, o, 16);
  float inv = 1.f/(den + 1e-16f);
  for (int e = e0 + g; e < e1; e += 16){
    int s = esrc[e]; if ((unsigned)s >= (unsigned)ns) s = 0;
    alpha[(long)e*4 + h] = __expf(lrelu(ss[(long)s*4 + h] + sdl) - m) * inv;
  }
}

// ---------------- aggregate-FIRST gather (r=2, all 4 heads, vectorized) ---
template<int NJ>
__global__ __launch_bounds__(256) void k_gather4(
    const BF16* __restrict__ A, const float* __restrict__ alpha,
    const int* __restrict__ indptr, const int* __restrict__ esrc,
    BF16* __restrict__ G, int n_dst, int Din, int E, int ns)
{
  int wid = (blockIdx.x*blockDim.x + threadIdx.x) >> 6;
  int lane = threadIdx.x & 63;
  if (wid >= n_dst) return;
  int e0 = indptr[wid], e1 = indptr[wid+1];
  e0 = max(0, min(e0, E)); e1 = max(e0, min(e1, E));
  float acc[4][NJ];
  #pragma unroll
  for (int h = 0; h < 4; ++h)
    #pragma unroll
    for (int j = 0; j < NJ; ++j) acc[h][j] = 0.f;
  for (int e = e0; e < e1; ++e){
    int s = esrc[e]; if ((unsigned)s >= (unsigned)ns) s = 0;
    float a0 = alpha[(long)e*4 + 0], a1 = alpha[(long)e*4 + 1];
    float a2 = alpha[(long)e*4 + 2], a3 = alpha[(long)e*4 + 3];
    const BF16* ar = A + (long)s*Din;
    if (NJ == 8){
      short8 v = *(const short8*)(ar + lane*8);
      #pragma unroll
      for (int j = 0; j < NJ; ++j){
        float x = bf2f(v[j]);
        acc[0][j] += a0*x; acc[1][j] += a1*x; acc[2][j] += a2*x; acc[3][j] += a3*x;
      }
    } else {
      ushort2 v = *(const ushort2*)(ar + lane*2);
      float x0 = bf2f((short)v.x), x1 = bf2f((short)v.y);
      acc[0][0] += a0*x0; acc[1][0] += a1*x0; acc[2][0] += a2*x0; acc[3][0] += a3*x0;
      acc[0][1] += a0*x1; acc[1][1] += a1*x1; acc[2][1] += a2*x1; acc[3][1] += a3*x1;
    }
  }
  #pragma unroll
  for (int h = 0; h < 4; ++h){
    if (NJ == 8){
      short8 g;
      #pragma unroll
      for (int j = 0; j < NJ; ++j) g[j] = (short)f2bf(acc[h][j]);
      *(short8*)(G + ((long)wid*4 + h)*Din + lane*8) = g;
    } else {
      ushort2 g;
      g.x = f2bf(acc[h][0]); g.y = f2bf(acc[h][1]);
      *(ushort2*)(G + ((long)wid*4 + h)*Din + lane*2) = g;
    }
  }
}

// ---------------- aggregation body (vectorized ushort2 for NJ==2) ---------
template<int NJ>
__device__ __forceinline__ void agg_body(
    const BF16* __restrict__ Zt, const float* __restrict__ alpha,
    const int* __restrict__ indptr, const int* __restrict__ esrc,
    float* acc, int wid, int lane, int TW, int head0, int E, int ns)
{
  int e0 = indptr[wid], e1 = indptr[wid+1];
  e0 = max(0, min(e0, E)); e1 = max(e0, min(e1, E));
  for (int e = e0; e < e1; ++e){
    int s = esrc[e]; if ((unsigned)s >= (unsigned)ns) s = 0;
    float aA = alpha[(long)e*4 + head0];
    const BF16* zr = Zt + (long)s*TW;
    if (NJ == 2){
      ushort2 z = *(const ushort2*)(zr + lane*2);
      acc[0] += aA * bf2f((short)z.x);
      acc[1] += aA * bf2f((short)z.y);
    } else {
      acc[0] += aA * ldE(zr, lane);
    }
  }
}

// ---------------- fused 2-relation aggregation (phase 1, dst=acc) ---------
template<int NJ>
__global__ __launch_bounds__(256) void k_agg2(
    const BF16* __restrict__ Z0, const BF16* __restrict__ Z1,
    const float* __restrict__ a0, const float* __restrict__ a1,
    const int* __restrict__ ip0, const int* __restrict__ ip1,
    const int* __restrict__ es0, const int* __restrict__ es1,
    BF16* __restrict__ out, int ldc, int c0w, int TW, int head0,
    int n_dst, int E, int ns0, int ns1)
{
  int wid = (blockIdx.x*blockDim.x + threadIdx.x) >> 6;
  int lane = threadIdx.x & 63;
  if (wid >= n_dst) return;
  float acc[NJ];
  #pragma unroll
  for (int j = 0; j < NJ; ++j) acc[j] = 0.f;
  agg_body<NJ>(Z0, a0, ip0, es0, acc, wid, lane, TW, head0, E, ns0);
  agg_body<NJ>(Z1, a1, ip1, es1, acc, wid, lane, TW, head0, E, ns1);
  if (NJ == 2){
    ushort2 g; g.x = f2bf(acc[0]); g.y = f2bf(acc[1]);
    *(ushort2*)(out + (long)wid*ldc + c0w + lane*2) = g;
  } else {
    stE(out, (long)wid*ldc + c0w + lane, acc[0]);
  }
}

// ---------------- fused 3-relation aggregation (phase 2, dst=tx) ----------
template<int NJ>
__global__ __launch_bounds__(256) void k_agg3(
    const BF16* __restrict__ Z0, const BF16* __restrict__ Z1, const BF16* __restrict__ Z2,
    const float* __restrict__ a0, const float* __restrict__ a1, const float* __restrict__ a2,
    const int* __restrict__ ip0, const int* __restrict__ ip1, const int* __restrict__ ip2,
    const int* __restrict__ es0, const int* __restrict__ es1, const int* __restrict__ es2,
    BF16* __restrict__ out, int ldc, int TW, int head0,
    int n_dst, int E, int ns0, int ns1, int ns2)
{
  int wid = (blockIdx.x*blockDim.x + threadIdx.x) >> 6;
  int lane = threadIdx.x & 63;
  if (wid >= n_dst) return;
  float acc[NJ];
  #pragma unroll
  for (int j = 0; j < NJ; ++j) acc[j] = 0.f;
  agg_body<NJ>(Z0, a0, ip0, es0, acc, wid, lane, TW, head0, E, ns0);
  agg_body<NJ>(Z1, a1, ip1, es1, acc, wid, lane, TW, head0, E, ns1);
  agg_body<NJ>(Z2, a2, ip2, es2, acc, wid, lane, TW, head0, E, ns2);
  if (NJ == 2){
    ushort2 g; g.x = f2bf(acc[0]); g.y = f2bf(acc[1]);
    *(ushort2*)(out + (long)wid*ldc + lane*2) = g;
  } else {
    stE(out, (long)wid*ldc + lane, acc[0]);
  }
}

// ---------------- BN stats over nw_tile [N, TW] bf16 (short8) -------------
__global__ void k_bnp(const BF16* __restrict__ nw, float* __restrict__ bnp,
                      int N, int TW, int P)
{
  int cpr  = TW/8;
  int col  = (threadIdx.x % cpr)*8;
  int slot = threadIdx.x / cpr;
  int rpb  = 256 / cpr;
  int p    = blockIdx.x*rpb + slot;
  float s[8] = {}, s2[8] = {};
  for (long r = p; r < N; r += P){
    short8 v = *(const short8*)(nw + r*TW + col);
    #pragma unroll
    for (int k = 0; k < 8; ++k){
      float x = bf2f(v[k]);
      s[k] += x; s2[k] += x*x;
    }
  }
  #pragma unroll
  for (int k = 0; k < 8; ++k){
    bnp[(long)p*2*TW + col + k]      = s[k];
    bnp[(long)p*2*TW + TW + col + k] = s2[k];
  }
}
__global__ void k_bnf(const float* __restrict__ bnp, float* __restrict__ bns,
                      int P, int TW)
{
  int c = blockIdx.x*256 + threadIdx.x;
  if (c >= 2*TW) return;
  float s = 0.f;
  for (int p = 0; p < P; ++p) s += bnp[(long)p*2*TW + c];
  bns[c] = s;
}
// ---------------- BN apply (short8, 8 elems/thread) -----------------------
__global__ void k_bn_apply(const BF16* __restrict__ nw, const float* __restrict__ bns,
                           const float* __restrict__ g, const float* __restrict__ b,
                           BF16* __restrict__ A, int N, int TW, int c0, int res)
{
  long total8 = (long)N*TW/8;
  for (long i8 = (long)blockIdx.x*blockDim.x + threadIdx.x; i8 < total8;
       i8 += (long)gridDim.x*blockDim.x){
    long i = i8*8;
    int col = (int)(i % TW);
    long r  = i / TW;
    short8 nv = *(const short8*)(nw + i);
    long ai = r*512 + c0 + col;
    short8 av;
    if (res) av = *(const short8*)(A + ai);
    short8 ov;
    #pragma unroll
    for (int k = 0; k < 8; ++k){
      int gc = c0 + col + k;
      float mu  = bns[col+k] / (float)N;
      float var = bns[TW + col + k] / (float)N - mu*mu;
      float sc = g[gc] * rsqrtf(var + 1e-5f);
      float sh = b[gc] - mu*sc;
      float v = fmaxf(bf2f(nv[k])*sc + sh, 0.f);
      if (res) v += bf2f(av[k]);
      ov[k] = (short)f2bf(v);
    }
    *(short8*)(A + ai) = ov;
  }
}

// ---------------- acc/mer update (short8) ----------------
__global__ void k_update(const BF16* __restrict__ B, const float* __restrict__ ab1,
                         const float* __restrict__ ab2, BF16* __restrict__ A,
                         long n512, int res)
{
  long n8 = n512/8;
  for (long i8 = (long)blockIdx.x*blockDim.x + threadIdx.x; i8 < n8;
       i8 += (long)gridDim.x*blockDim.x){
    long i = i8*8;
    int c = (int)(i & 511);
    short8 bv = *(const short8*)(B + i);
    short8 av;
    if (res) av = *(const short8*)(A + i);
    short8 ov;
    #pragma unroll
    for (int k = 0; k < 8; ++k){
      float v = bf2f(bv[k]) + ab1[c+k] + (ab2 ? ab2[c+k] : 0.f);
      v = fmaxf(v, 0.f);
      if (res) v += bf2f(av[k]);
      ov[k] = (short)f2bf(v);
    }
    *(short8*)(A + i) = ov;
  }
}

// ---------------- head logits ----------------
__global__ void k_logits(const BF16* __restrict__ Hid, const float* __restrict__ Wh2,
                         const float* __restrict__ bh2, float* __restrict__ out, int N)
{
  int node = (blockIdx.x*blockDim.x + threadIdx.x) >> 6;
  int lane = threadIdx.x & 63;
  if (node >= N) return;
  float v = ldE(Hid, (long)node*64 + lane) * Wh2[lane];
  #pragma unroll
  for (int off = 32; off; off >>= 1) v += __shfl_down(v, off, 64);
  if (lane == 0) out[node] = v + bh2[0];
}

// ---------------------------------------------------------------------------
struct Arena {
  BF16 *A[3];
  BF16 *Bst[3];
  BF16 *Zt;
  BF16 *blkB;
  BF16 *hidden;
  float *scoreS, *scoreD;
  float *alpha;
  float *Fbuf;
  float *bnp, *bns;
  int *counts, *bsums;
  int *indptr[6], *esrc[6];
  BF16 *Wt0[6], *WtL[2][6], *Wh1t;
  size_t total;
};

extern "C" void kernel_launch(void* const* d_in, const int* in_sizes, int n_in,
                              void* d_out, int out_size, void* d_ws, size_t ws_size,
                              hipStream_t stream)
{
  const float* x_tx  = (const float*)d_in[0];
  const float* x_acc = (const float*)d_in[1];
  const float* x_mer = (const float*)d_in[2];
  const float* Wtx = (const float*)d_in[3];  const float* btx  = (const float*)d_in[4];
  const float* Wacc= (const float*)d_in[5];  const float* bacc = (const float*)d_in[6];
  const float* Wmer= (const float*)d_in[7];  const float* bmer = (const float*)d_in[8];
  const float* W0   = (const float*)d_in[9];
  const float* Wrest= (const float*)d_in[10];
  const float* att_s= (const float*)d_in[11];
  const float* att_d= (const float*)d_in[12];
  const float* att_b= (const float*)d_in[13];
  const float* bn_g = (const float*)d_in[14];
  const float* bn_b = (const float*)d_in[15];
  const float* Wh1  = (const float*)d_in[16]; const float* bh1 = (const float*)d_in[17];
  const float* Wh2  = (const float*)d_in[18]; const float* bh2 = (const float*)d_in[19];
  const int*   edges= (const int*)d_in[20];

  const int E    = in_sizes[20] / 12;
  const int nTx  = in_sizes[0] / 64;
  const int nAcc = in_sizes[1] / 32;
  const int nMer = in_sizes[2] / 32;
  const int nOf[3]   = {nTx, nAcc, nMer};
  const int SRC_T[6] = {0,0,0,1,1,2};
  const int DST_T[6] = {1,1,2,0,0,0};
  const int maxN = max(nTx, max(nAcc, nMer));
  (void)n_in;

  auto layout = [&](int TW)->Arena{
    Arena P{};
    size_t off = 0;
    auto a = [&](size_t bytes)->char*{
      char* p = (char*)d_ws + off;
      off += (bytes + 255) & ~(size_t)255;
      return p;
    };
    auto al = [](size_t b){ return (b + 255) & ~(size_t)255; };
    P.A[0]   = (BF16*)a((size_t)nTx *512*2);
    P.A[1]   = (BF16*)a((size_t)nAcc*512*2);
    P.A[2]   = (BF16*)a((size_t)nMer*512*2);
    P.Bst[1] = (BF16*)a((size_t)nAcc*512*2);
    P.Bst[2] = (BF16*)a((size_t)nMer*512*2);
    size_t zrowsA = (size_t)maxN > (size_t)2*nAcc + nMer ? (size_t)maxN : (size_t)2*nAcc + nMer;
    size_t blkA = al(zrowsA*TW*2);
    size_t blkBsz = al((size_t)nTx*TW*2);
    size_t gB = al((size_t)nMer*4*512*2);
    if (gB > blkBsz) blkBsz = gB;
    size_t scoreB = al((size_t)3*maxN*4*4)*2;
    size_t hidB = al((size_t)nTx*64*2);
    size_t scr = blkA + blkBsz;
    if (scr < scoreB) scr = scoreB;
    if (scr < hidB)   scr = hidB;
    char* scrBase = a(scr);
    P.Zt     = (BF16*)scrBase;
    P.blkB   = (BF16*)(scrBase + blkA);
    P.scoreS = (float*)scrBase;
    P.scoreD = (float*)(scrBase + al((size_t)3*maxN*4*4));
    P.hidden = (BF16*)scrBase;
    P.alpha  = (float*)a((size_t)3*E*4*4);
    P.Fbuf   = (float*)a((size_t)6*8*512*4);
    P.bnp    = (float*)a(1048576);
    P.bns    = (float*)a(4096);
    P.counts = (int*)a((size_t)maxN*4);
    P.bsums  = (int*)a(4096);
    for (int r = 0; r < 6; ++r){
      P.indptr[r] = (int*)a((size_t)(nOf[DST_T[r]]+1)*4);
      P.esrc[r]   = (int*)a((size_t)E*4);
    }
    for (int r = 0; r < 6; ++r) P.Wt0[r] = (BF16*)a((size_t)512*128*2);
    for (int l = 0; l < 2; ++l)
      for (int r = 0; r < 6; ++r) P.WtL[l][r] = (BF16*)a((size_t)512*512*2);
    P.Wh1t = (BF16*)a((size_t)64*512*2);
    P.total = off;
    return P;
  };

  int TW = 0;
  Arena P{};
  for (int cand : {128, 64}){
    P = layout(cand);
    if (P.total <= ws_size){ TW = cand; break; }
  }
  if (TW == 0){
    float sentinel = 10000.0f + (float)(ws_size >> 20);
    k_fill_f32<<<dim3((out_size+255)/256), dim3(256), 0, stream>>>((float*)d_out, (long)out_size, sentinel);
    return;
  }
  const int nTiles = 512 / TW;
  const int NJv = TW/64;
  const int PBX = 64, Pp = PBX * (256/(TW/8));
  dim3 b256(256);

  // ---- 0. weight prep (3 batched launches) ----
  k_wt<<<dim3(16,4,6),  b256, 0, stream>>>(W0,    P.Wt0[0],    128, 512);
  k_wt<<<dim3(16,16,12),b256, 0, stream>>>(Wrest, P.WtL[0][0], 512, 512);
  k_wt<<<dim3(2,16,1),  b256, 0, stream>>>(Wh1,   P.Wh1t,      512, 64);

  auto mfma_gemm = [&](const BF16* A, const BF16* Bt, BF16* Cp, int M, int K, int c0, int ldc){
    if (TW >= 128)
      k_mfma<128,2,2,4,4,BF16><<<dim3(TW/128,(M+127)/128,1),b256,0,stream>>>(
          A, Bt, Cp, M, K, c0, ldc, K, (const float*)nullptr, 0, 0, 0L, 0L, 0, (const BF16*)nullptr);
    else
      k_mfma<64,4,1,2,4,BF16><<<dim3(1,(M+127)/128,1),b256,0,stream>>>(
          A, Bt, Cp, M, K, c0, ldc, K, (const float*)nullptr, 0, 0, 0L, 0L, 0, (const BF16*)nullptr);
  };
  auto mfma_pair = [&](const BF16* A, const BF16* Bt0, const BF16* Bt1p, BF16* Cp, long cZst,
                       int M, int K, int c0){
    if (TW >= 128)
      k_mfma<128,2,2,4,4,BF16><<<dim3(TW/128,(M+127)/128,2),b256,0,stream>>>(
          A, Bt0, Cp, M, K, c0, TW, K, (const float*)nullptr, 0, 0, 0L, cZst, 0, Bt1p);
    else {
      mfma_gemm(A, Bt0, Cp, M, K, c0, TW);
      mfma_gemm(A, Bt1p, Cp + cZst, M, K, c0, TW);
    }
  };

  // ---- 1. CSR build (per-relation) ----
  for (int r = 0; r < 6; ++r){
    int nd = nOf[DST_T[r]], ns = nOf[SRC_T[r]];
    const int* srcP = edges + (size_t)r*2*E;
    const int* dstP = srcP + E;
    int nb = (nd + 255)/256;
    k_zero   <<<dim3(nb),          b256, 0, stream>>>(P.counts, (long)nd);
    k_hist   <<<dim3((E+255)/256), b256, 0, stream>>>(dstP, P.counts, E, nd);
    k_scan1  <<<dim3(nb),          b256, 0, stream>>>(P.counts, P.indptr[r], P.bsums, nd);
    k_scan2  <<<dim3(1),           dim3(1024),0, stream>>>(P.bsums, nb);
    k_scan3  <<<dim3(nb),          b256, 0, stream>>>(P.indptr[r], P.bsums, nd);
    k_zero   <<<dim3(nb),          b256, 0, stream>>>(P.counts, (long)nd);
    k_scatter<<<dim3((E+255)/256), b256, 0, stream>>>(srcP, dstP, P.indptr[r], P.counts, P.esrc[r], E, nd, ns);
  }

  // ---- 2. encoders ----
  k_gemm<float,BF16><<<dim3(2,(nTx +63)/64), b256, 0, stream>>>(x_tx,  Wtx,  P.A[0], nTx,  128, 64, 128, btx,  1);
  k_gemm<float,BF16><<<dim3(2,(nAcc+63)/64), b256, 0, stream>>>(x_acc, Wacc, P.A[1], nAcc, 128, 32, 128, bacc, 1);
  k_gemm<float,BF16><<<dim3(2,(nMer+63)/64), b256, 0, stream>>>(x_mer, Wmer, P.A[2], nMer, 128, 32, 128, bmer, 1);

  const long mS = (long)maxN*4;
  // ---- 3. layers ----
  for (int i = 0; i < 3; ++i){
    const int Din = (i == 0) ? 128 : 512;
    const int res = (i > 0) ? 1 : 0;
    const long fstr = 8L*Din;
    const float* WbaseL = (i == 0) ? W0 : (Wrest + (size_t)(i-1)*6*512*512);
    const long wstride = (i == 0) ? 128L*512 : 512L*512;
    auto Wtof = [&](int r)->const BF16*{ return (i == 0) ? P.Wt0[r] : P.WtL[i-1][r]; };

    k_foldAll<<<dim3(48*Din/4), b256, 0, stream>>>(WbaseL, wstride,
        att_s + (size_t)i*6*512, att_d + (size_t)i*6*512, P.Fbuf, Din);

    // ---- Phase 1: scores, then ALL alphas (batched) ----
    k_scoreM<3><<<dim3((nTx+15)/16), b256, 0, stream>>>(P.A[0], P.Fbuf,           fstr, P.scoreS, mS, nTx, Din);
    k_scoreM<2><<<dim3((nAcc+15)/16), b256, 0, stream>>>(P.A[1], P.Fbuf + 4*Din,  fstr, P.scoreD, mS, nAcc, Din);
    k_scoreM<1><<<dim3((nMer+15)/16), b256, 0, stream>>>(P.A[2], P.Fbuf + 20*Din, fstr, P.scoreD + 2*mS, 0, nMer, Din);
    {
      AlphaArgs aa{};
      int ndMax = 0;
      for (int r = 0; r < 3; ++r){
        aa.ss[r] = P.scoreS + r*mS; aa.sd[r] = P.scoreD + r*mS;
        aa.ip[r] = P.indptr[r]; aa.es[r] = P.esrc[r];
        aa.al[r] = P.alpha + (size_t)r*E*4;
        aa.nd[r] = nOf[DST_T[r]]; aa.ns[r] = nTx;
        if (aa.nd[r] > ndMax) ndMax = aa.nd[r];
      }
      k_alpha3b<<<dim3((ndMax+3)/4,3), b256, 0, stream>>>(aa, E);
    }
    // r=2 (tx->mer): aggregate-FIRST; 4 head-GEMMs in one z=4 launch
    {
      BF16* Gm = P.blkB;
      if (Din == 512)
        k_gather4<8><<<dim3((nMer+3)/4), b256, 0, stream>>>(P.A[0], P.alpha + (size_t)2*E*4,
            P.indptr[2], P.esrc[2], Gm, nMer, Din, E, nTx);
      else
        k_gather4<2><<<dim3((nMer+3)/4), b256, 0, stream>>>(P.A[0], P.alpha + (size_t)2*E*4,
            P.indptr[2], P.esrc[2], Gm, nMer, Din, E, nTx);
      k_mfma<128,2,2,4,4,BF16><<<dim3(1,(nMer+127)/128,4), b256, 0, stream>>>(
          Gm, Wtof(2), P.Bst[2], nMer, Din, 0, 512, 4*Din,
          (const float*)nullptr, 0, 0, (long)Din, 128L, 128, (const BF16*)nullptr);
    }
    // r=0,1 (tx->acc): z=2 pair GEMM + fused agg2
    {
      BF16* Zr0 = P.Zt;
      BF16* Zr1 = P.blkB;
      long zst = (long)(Zr1 - Zr0);
      for (int t = 0; t < nTiles; ++t){
        int c0 = t*TW;
        mfma_pair(P.A[0], Wtof(0), Wtof(1), Zr0, zst, nTx, Din, c0);
        dim3 ga((nAcc+3)/4);
        if (NJv == 2)
          k_agg2<2><<<ga,b256,0,stream>>>(Zr0, Zr1, P.alpha, P.alpha + (size_t)E*4,
              P.indptr[0], P.indptr[1], P.esrc[0], P.esrc[1],
              P.Bst[1], 512, c0, TW, c0>>7, nAcc, E, nTx, nTx);
        else
          k_agg2<1><<<ga,b256,0,stream>>>(Zr0, Zr1, P.alpha, P.alpha + (size_t)E*4,
              P.indptr[0], P.indptr[1], P.esrc[0], P.esrc[1],
              P.Bst[1], 512, c0, TW, c0>>7, nAcc, E, nTx, nTx);
      }
    }

    // ---- Phase 2 (dst=tx; src=acc r=3,4; mer r=5) ----
    k_scoreM<2><<<dim3((nAcc+15)/16), b256, 0, stream>>>(P.A[1], P.Fbuf + 24*Din, fstr, P.scoreS, mS, nAcc, Din);
    k_scoreM<1><<<dim3((nMer+15)/16), b256, 0, stream>>>(P.A[2], P.Fbuf + 40*Din, fstr, P.scoreS + 2*mS, 0, nMer, Din);
    k_scoreM<3><<<dim3((nTx+15)/16), b256, 0, stream>>>(P.A[0], P.Fbuf + 28*Din, fstr, P.scoreD, mS, nTx, Din);
    {
      AlphaArgs aa{};
      for (int q = 0; q < 3; ++q){
        int r = 3 + q;
        aa.ss[q] = P.scoreS + q*mS; aa.sd[q] = P.scoreD + q*mS;
        aa.ip[q] = P.indptr[r]; aa.es[q] = P.esrc[r];
        aa.al[q] = P.alpha + (size_t)q*E*4;
        aa.nd[q] = nTx; aa.ns[q] = nOf[SRC_T[r]];
      }
      k_alpha3b<<<dim3((nTx+3)/4,3), b256, 0, stream>>>(aa, E);
    }
    BF16* Z3 = P.Zt;
    BF16* Z4 = P.Zt + (size_t)nAcc*TW;
    BF16* Z5 = P.Zt + (size_t)2*nAcc*TW;
    BF16* nw = P.blkB;
    for (int t = 0; t < nTiles; ++t){
      int c0 = t*TW;
      mfma_pair(P.A[1], Wtof(3), Wtof(4), Z3, (long)nAcc*TW, nAcc, Din, c0);
      mfma_gemm(P.A[2], Wtof(5), Z5, nMer, Din, c0, TW);
      dim3 ga((nTx+3)/4);
      if (NJv == 2)
        k_agg3<2><<<ga,b256,0,stream>>>(Z3,Z4,Z5, P.alpha, P.alpha+(size_t)E*4, P.alpha+(size_t)2*E*4,
            P.indptr[3],P.indptr[4],P.indptr[5], P.esrc[3],P.esrc[4],P.esrc[5],
            nw, TW, TW, c0>>7, nTx, E, nAcc, nAcc, nMer);
      else
        k_agg3<1><<<ga,b256,0,stream>>>(Z3,Z4,Z5, P.alpha, P.alpha+(size_t)E*4, P.alpha+(size_t)2*E*4,
            P.indptr[3],P.indptr[4],P.indptr[5], P.esrc[3],P.esrc[4],P.esrc[5],
            nw, TW, TW, c0>>7, nTx, E, nAcc, nAcc, nMer);
      k_bnp<<<dim3(PBX), b256, 0, stream>>>(nw, P.bnp, nTx, TW, Pp);
      k_bnf<<<dim3((2*TW+255)/256), b256, 0, stream>>>(P.bnp, P.bns, Pp, TW);
      k_bn_apply<<<dim3(2048), b256, 0, stream>>>(nw, P.bns,
          bn_g + (size_t)i*512, bn_b + (size_t)i*512, P.A[0], nTx, TW, c0, res);
    }
    // ---- Phase 3 ----
    const float* ab0 = att_b + ((size_t)(i*6 + 0))*512;
    const float* ab1 = att_b + ((size_t)(i*6 + 1))*512;
    const float* ab2 = att_b + ((size_t)(i*6 + 2))*512;
    k_update<<<dim3(1024), b256, 0, stream>>>(P.Bst[1], ab0, ab1, P.A[1], (long)nAcc*512, res);
    k_update<<<dim3(128),  b256, 0, stream>>>(P.Bst[2], ab2, (const float*)nullptr, P.A[2], (long)nMer*512, res);
  }

  // ---- 4. head ----
  k_mfma<64,4,1,2,4,BF16><<<dim3(1,(nTx+127)/128,1), b256, 0, stream>>>(
      P.A[0], P.Wh1t, P.hidden, nTx, 512, 0, 64, 512, bh1, 1, 0,
      0L, 0L, 0, (const BF16*)nullptr);
  k_logits<<<dim3((nTx+3)/4), b256, 0, stream>>>(P.hidden, Wh2, bh2, (float*)d_out, nTx);
}

// Round 19
// 10124.538 us; speedup vs baseline: 1.8042x; 1.8042x over previous
//
#include <hip/hip_runtime.h>
#include <math.h>

// ---------------------------------------------------------------------------
// FraudGAT: bf16 storage, MFMA projections, pre-transposed bf16 weights.
// R19 = R16 restored byte-for-byte (known good, 10.11 ms, arena 284.25 MB).
// R17/R18 regressions were a workspace TIER DROP (bnp 256KB->1MB pushed the
// arena past ws_size at TW=128 -> TW=64 -> ~1.8x slowdown), NOT the GEMM
// staging. ws_size is inferred to be in [284.25, 285.0) MB -- every future
// layout change must re-verify the TW=128 tier fits.
// ---------------------------------------------------------------------------

typedef unsigned short BF16;
typedef short short8 __attribute__((ext_vector_type(8)));
typedef float f32x4 __attribute__((ext_vector_type(4)));
typedef __bf16 bf16x8 __attribute__((ext_vector_type(8)));

static __device__ __forceinline__ float lrelu(float x){ return x > 0.f ? x : 0.2f*x; }

__device__ __forceinline__ float ldE(const float* p, long i){ return p[i]; }
__device__ __forceinline__ float ldE(const BF16* p, long i){
  return __uint_as_float((unsigned)p[i] << 16);
}
__device__ __forceinline__ void stE(float* p, long i, float v){ p[i] = v; }
__device__ __forceinline__ void stE(BF16* p, long i, float v){
  unsigned u = __float_as_uint(v);
  p[i] = (BF16)((u + 0x7FFFu + ((u >> 16) & 1u)) >> 16);
}
__device__ __forceinline__ BF16 f2bf(float v){
  unsigned u = __float_as_uint(v);
  return (BF16)((u + 0x7FFFu + ((u >> 16) & 1u)) >> 16);
}
__device__ __forceinline__ float bf2f(short s){
  return __uint_as_float((unsigned)(unsigned short)s << 16);
}
__device__ __forceinline__ float4 ld4E(const float* p, long i){ return *(const float4*)(p + i); }
__device__ __forceinline__ float4 ld4E(const BF16* p, long i){
  ushort4 s = *(const ushort4*)(p + i);
  return make_float4(__uint_as_float((unsigned)s.x<<16), __uint_as_float((unsigned)s.y<<16),
                     __uint_as_float((unsigned)s.z<<16), __uint_as_float((unsigned)s.w<<16));
}

// ---------------- utility ----------------
__global__ void k_zero(int* __restrict__ p, long n){
  long i = (long)blockIdx.x*blockDim.x + threadIdx.x;
  if (i < n) p[i] = 0;
}
__global__ void k_fill_f32(float* __restrict__ p, long n, float v){
  long i = (long)blockIdx.x*blockDim.x + threadIdx.x;
  if (i < n) p[i] = v;
}

// ---------------- weight transpose+convert (z-batched) --------------------
__global__ __launch_bounds__(256) void k_wt(const float* __restrict__ in, BF16* __restrict__ out,
                                            int K, int N)
{
  in  += (long)blockIdx.z*K*N;
  out += (long)blockIdx.z*N*K;
  __shared__ float t[32][33];
  int kb = blockIdx.y*32, nb = blockIdx.x*32;
  int tx = threadIdx.x & 31, ty8 = threadIdx.x >> 5;
  for (int j = ty8; j < 32; j += 8){
    int k = kb + j, n = nb + tx;
    t[j][tx] = (k < K && n < N) ? in[(long)k*N + n] : 0.f;
  }
  __syncthreads();
  for (int j = ty8; j < 32; j += 8){
    int n = nb + j, k = kb + tx;
    if (n < N && k < K) out[(long)n*K + k] = f2bf(t[tx][j]);
  }
}

// ---------------- fold ALL 12 tables in one launch ------------------------
__global__ __launch_bounds__(256) void k_foldAll(
    const float* __restrict__ Wbase, long wstride,
    const float* __restrict__ atts, const float* __restrict__ attd,
    float* __restrict__ F, int Din)
{
  int w = (blockIdx.x*256 + threadIdx.x) >> 6;
  int lane = threadIdx.x & 63;
  int total = 48*Din;
  if (w >= total) return;
  int k = w % Din;
  int rem = w / Din;
  int h = rem & 3, sd = (rem >> 2) & 1, r = rem >> 3;
  const float* wr = Wbase + (long)r*wstride + (long)k*512 + h*128;
  const float* ar = (sd ? attd : atts) + r*512 + h*128;
  float p = wr[lane]*ar[lane] + wr[lane+64]*ar[lane+64];
  #pragma unroll
  for (int off = 32; off; off >>= 1) p += __shfl_down(p, off, 64);
  if (lane == 0) F[(long)((r*2+sd)*4 + h)*Din + k] = p;
}

// ---------------- MFMA GEMM (reg staging, LSTR=72 pad; optionally z-batched)
template<int BN, int WM, int WN, int FM, int FN, typename TC>
__global__ __launch_bounds__(256) void k_mfma(
    const BF16* __restrict__ A, const BF16* __restrict__ Bt, TC* __restrict__ C,
    int M, int K, int c0, int ldc, int lda, const float* __restrict__ bias,
    int doRelu, int accum, long aZst, long cZst, int c0Zst, const BF16* __restrict__ Bt1)
{
  constexpr int BM = 128;
  constexpr int LSTR = 72;
  __shared__ __attribute__((aligned(16))) short Als[BM][LSTR];
  __shared__ __attribute__((aligned(16))) short Bls[BN][LSTR];
  const int z = blockIdx.z;
  A += (long)z*aZst;
  C += (long)z*cZst;
  c0 += z*c0Zst;
  if (z >= 1 && Bt1) Bt = Bt1;
  const int bn0 = blockIdx.x * BN;
  const int bm = blockIdx.y*BM;
  const int tid = threadIdx.x;
  const int wave = tid >> 6, lane = tid & 63;
  const int wr = wave / WN, wc = wave % WN;
  const int lrow = lane & 15, kg = lane >> 4;
  f32x4 acc[FM][FN] = {};
  for (int k0 = 0; k0 < K; k0 += 64){
    #pragma unroll
    for (int t = 0; t < 4; ++t){
      int idx = tid + t*256;
      int row = idx >> 3, kc = (idx & 7) << 3;
      int gr = bm + row;
      short8 v = {};
      if (gr < M) v = *(const short8*)(A + (long)gr*lda + k0 + kc);
      *(short8*)&Als[row][kc] = v;
    }
    #pragma unroll
    for (int t = 0; t < BN/32; ++t){
      int idx = tid + t*256;
      int row = idx >> 3, kc = (idx & 7) << 3;
      *(short8*)&Bls[row][kc] = *(const short8*)(Bt + (long)(c0+bn0+row)*K + k0 + kc);
    }
    __syncthreads();
    #pragma unroll
    for (int kk = 0; kk < 2; ++kk){
      short8 af[FM], bq[FN];
      #pragma unroll
      for (int m = 0; m < FM; ++m)
        af[m] = *(const short8*)&Als[wr*FM*16 + m*16 + lrow][kk*32 + kg*8];
      #pragma unroll
      for (int n = 0; n < FN; ++n)
        bq[n] = *(const short8*)&Bls[wc*FN*16 + n*16 + lrow][kk*32 + kg*8];
      #pragma unroll
      for (int m = 0; m < FM; ++m)
        #pragma unroll
        for (int n = 0; n < FN; ++n)
          acc[m][n] = __builtin_amdgcn_mfma_f32_16x16x32_bf16(
              __builtin_bit_cast(bf16x8, af[m]), __builtin_bit_cast(bf16x8, bq[n]),
              acc[m][n], 0, 0, 0);
    }
    __syncthreads();
  }
  // epilogue: C/D layout col=lane&15, row=(lane>>4)*4+reg  [m89]
  #pragma unroll
  for (int m = 0; m < FM; ++m){
    #pragma unroll
    for (int n = 0; n < FN; ++n){
      #pragma unroll
      for (int j = 0; j < 4; ++j){
        int row = bm + wr*FM*16 + m*16 + kg*4 + j;
        if (row >= M) continue;
        int col = wc*FN*16 + n*16 + lrow;
        float v = acc[m][n][j];
        if (bias) v += bias[bn0 + col];
        if (doRelu) v = fmaxf(v, 0.f);
        long idx = (long)row*ldc + bn0 + col;
        if (accum) v += ldE(C, idx);
        stE(C, idx, v);
      }
    }
  }
}

// ---------------- naive GEMM (f32 A) for the tiny encoders ----------------
template<typename TA, typename TC>
__global__ __launch_bounds__(256) void k_gemm(
    const TA* __restrict__ A, const float* __restrict__ B, TC* __restrict__ C,
    int M, int N, int K, int ldb, const float* __restrict__ bias, int doRelu)
{
  __shared__ float As[16][64];
  __shared__ float Bs[16][64];
  const int bm = blockIdx.y*64, bn = blockIdx.x*64;
  const int tid = threadIdx.x;
  const int ty = tid >> 4, tx = tid & 15;
  const int ar = tid >> 2;
  const int ac = (tid & 3) << 2;
  const int br = tid >> 4;
  const int bc = (tid & 15) << 2;
  float acc[4][4] = {};
  for (int k0 = 0; k0 < K; k0 += 16){
    int row = bm + ar;
    float4 av = make_float4(0.f,0.f,0.f,0.f);
    if (row < M) av = ld4E(A, (long)row*K + k0 + ac);
    As[ac+0][ar]=av.x; As[ac+1][ar]=av.y; As[ac+2][ar]=av.z; As[ac+3][ar]=av.w;
    float4 bv = make_float4(0.f,0.f,0.f,0.f);
    if (bn + bc + 3 < N) bv = *(const float4*)(B + (long)(k0+br)*ldb + bn + bc);
    *(float4*)&Bs[br][bc] = bv;
    __syncthreads();
    #pragma unroll
    for (int kk = 0; kk < 16; ++kk){
      float a[4], b[4];
      #pragma unroll
      for (int x = 0; x < 4; ++x){ a[x]=As[kk][ty*4+x]; b[x]=Bs[kk][tx*4+x]; }
      #pragma unroll
      for (int y = 0; y < 4; ++y)
        #pragma unroll
        for (int x = 0; x < 4; ++x) acc[y][x] += a[y]*b[x];
    }
    __syncthreads();
  }
  #pragma unroll
  for (int y = 0; y < 4; ++y){
    int row = bm + ty*4 + y;
    if (row >= M) continue;
    #pragma unroll
    for (int x = 0; x < 4; ++x){
      int col = bn + tx*4 + x;
      if (col >= N) continue;
      float v = acc[y][x];
      if (bias) v += bias[col];
      if (doRelu) v = fmaxf(v, 0.f);
      stE(C, (long)row*N + col, v);
    }
  }
}

// ---------------- merged scores: R relations, one pass over X -------------
template<int R>
__global__ __launch_bounds__(256) void k_scoreM(
    const BF16* __restrict__ X, const float* __restrict__ Ftab, long fstride,
    float* __restrict__ out, long ostride, int N, int Din)
{
  int wave = threadIdx.x >> 6, lane = threadIdx.x & 63;
  int node0 = blockIdx.x*16 + wave*4;
  if (node0 >= N) return;
  int base = lane*8;
  bool act = base < Din;
  float x[4][8];
  #pragma unroll
  for (int t = 0; t < 4; ++t){
    int node = node0 + t;
    if (act && node < N){
      short8 v = *(const short8*)(X + (long)node*Din + base);
      #pragma unroll
      for (int j = 0; j < 8; ++j) x[t][j] = bf2f(v[j]);
    } else {
      #pragma unroll
      for (int j = 0; j < 8; ++j) x[t][j] = 0.f;
    }
  }
  #pragma unroll
  for (int r = 0; r < R; ++r){
    const float* F = Ftab + (long)r*fstride;
    float p[4][4] = {};
    #pragma unroll
    for (int h = 0; h < 4; ++h){
      float f[8];
      if (act){
        float4 fa = *(const float4*)(F + h*Din + base);
        float4 fb = *(const float4*)(F + h*Din + base + 4);
        f[0]=fa.x; f[1]=fa.y; f[2]=fa.z; f[3]=fa.w;
        f[4]=fb.x; f[5]=fb.y; f[6]=fb.z; f[7]=fb.w;
      } else {
        #pragma unroll
        for (int j = 0; j < 8; ++j) f[j] = 0.f;
      }
      #pragma unroll
      for (int t = 0; t < 4; ++t)
        #pragma unroll
        for (int j = 0; j < 8; ++j) p[t][h] += x[t][j]*f[j];
    }
    #pragma unroll
    for (int t = 0; t < 4; ++t)
      #pragma unroll
      for (int h = 0; h < 4; ++h)
        #pragma unroll
        for (int off = 32; off; off >>= 1)
          p[t][h] += __shfl_down(p[t][h], off, 64);
    if (lane == 0){
      #pragma unroll
      for (int t = 0; t < 4; ++t){
        int node = node0 + t;
        if (node < N){
          #pragma unroll
          for (int h = 0; h < 4; ++h)
            out[(long)r*ostride + (long)node*4 + h] = p[t][h];
        }
      }
    }
  }
}

// ---------------- CSR build (per-relation) --------------------------------
__global__ void k_hist(const int* __restrict__ dst, int* __restrict__ counts, int E, int nd){
  int e = blockIdx.x*blockDim.x + threadIdx.x;
  if (e >= E) return;
  int d = dst[e];
  if ((unsigned)d < (unsigned)nd) atomicAdd(&counts[d], 1);
}
__global__ void k_scan1(const int* __restrict__ counts, int* __restrict__ indptr,
                        int* __restrict__ bsums, int n)
{
  __shared__ int sm[256];
  int i = blockIdx.x*256 + threadIdx.x;
  int v = (i < n) ? counts[i] : 0;
  sm[threadIdx.x] = v; __syncthreads();
  for (int off = 1; off < 256; off <<= 1){
    int t = (threadIdx.x >= off) ? sm[threadIdx.x - off] : 0;
    __syncthreads();
    sm[threadIdx.x] += t;
    __syncthreads();
  }
  if (i < n) indptr[i+1] = sm[threadIdx.x];
  if (threadIdx.x == 255) bsums[blockIdx.x] = sm[255];
  if (blockIdx.x == 0 && threadIdx.x == 0) indptr[0] = 0;
}
__global__ void k_scan2(int* __restrict__ bsums, int nb){
  __shared__ int sm[1024];
  int t = threadIdx.x;
  int v = (t < nb) ? bsums[t] : 0;
  sm[t] = v; __syncthreads();
  for (int off = 1; off < 1024; off <<= 1){
    int x = (t >= off) ? sm[t - off] : 0;
    __syncthreads();
    sm[t] += x;
    __syncthreads();
  }
  if (t < nb) bsums[t] = sm[t];
}
__global__ void k_scan3(int* __restrict__ indptr, const int* __restrict__ bsums, int n){
  if (blockIdx.x == 0) return;
  int i = blockIdx.x*256 + threadIdx.x;
  int add = bsums[blockIdx.x - 1];
  if (i < n) indptr[i+1] += add;
}
__global__ void k_scatter(const int* __restrict__ src, const int* __restrict__ dst,
                          const int* __restrict__ indptr, int* __restrict__ cursor,
                          int* __restrict__ esrc, int E, int nd, int ns)
{
  int e = blockIdx.x*blockDim.x + threadIdx.x;
  if (e >= E) return;
  int d = dst[e];
  if ((unsigned)d >= (unsigned)nd) return;
  int s = src[e];
  if ((unsigned)s >= (unsigned)ns) s = 0;
  int pos = indptr[d] + atomicAdd(&cursor[d], 1);
  if (pos >= 0 && pos < E) esrc[pos] = s;
}

// ---------------- batched per-edge alpha (3 relations, grid.y) ------------
struct AlphaArgs {
  const float* ss[3]; const float* sd[3];
  const int* ip[3]; const int* es[3];
  float* al[3]; int nd[3]; int ns[3];
};
__global__ __launch_bounds__(256) void k_alpha3b(AlphaArgs a, int E){
  int r = blockIdx.y;
  int wid = (blockIdx.x*blockDim.x + threadIdx.x) >> 6;
  int lane = threadIdx.x & 63;
  if (wid >= a.nd[r]) return;
  const int* indptr = a.ip[r];
  const int* esrc = a.es[r];
  const float* ss = a.ss[r];
  int ns = a.ns[r];
  int e0 = indptr[wid], e1 = indptr[wid+1];
  e0 = max(0, min(e0, E)); e1 = max(e0, min(e1, E));
  if (e0 >= e1) return;
  int h = lane >> 4, g = lane & 15;
  float sdl = a.sd[r][(long)wid*4 + h];
  float* alpha = a.al[r];
  float m = -INFINITY;
  for (int e = e0 + g; e < e1; e += 16){
    int s = esrc[e]; if ((unsigned)s >= (unsigned)ns) s = 0;
    m = fmaxf(m, lrelu(ss[(long)s*4 + h] + sdl));
  }
  #pragma unroll
  for (int o = 1; o < 16; o <<= 1) m = fmaxf(m, __shfl_xor(m, o, 16));
  float den = 0.f;
  for (int e = e0 + g; e < e1; e += 16){
    int s = esrc[e]; if ((unsigned)s >= (unsigned)ns) s = 0;
    den += __expf(lrelu(ss[(long)s*4 + h] + sdl) - m);
  }
  #pragma unroll
  for (int o = 1; o < 16; o <<= 1) den += __shfl_xor(den, o, 16);
  float inv = 1.f/(den + 1e-16f);
  for (int e = e0 + g; e < e1; e += 16){
    int s = esrc[e]; if ((unsigned)s >= (unsigned)ns) s = 0;
    alpha[(long)e*4 + h] = __expf(lrelu(ss[(long)s*4 + h] + sdl) - m) * inv;
  }
}

// ---------------- aggregate-FIRST gather (r=2, all 4 heads, vectorized) ---
template<int NJ>
__global__ __launch_bounds__(256) void k_gather4(
    const BF16* __restrict__ A, const float* __restrict__ alpha,
    const int* __restrict__ indptr, const int* __restrict__ esrc,
    BF16* __restrict__ G, int n_dst, int Din, int E, int ns)
{
  int wid = (blockIdx.x*blockDim.x + threadIdx.x) >> 6;
  int lane = threadIdx.x & 63;
  if (wid >= n_dst) return;
  int e0 = indptr[wid], e1 = indptr[wid+1];
  e0 = max(0, min(e0, E)); e1 = max(e0, min(e1, E));
  float acc[4][NJ];
  #pragma unroll
  for (int h = 0; h < 4; ++h)
    #pragma unroll
    for (int j = 0; j < NJ; ++j) acc[h][j] = 0.f;
  for (int e = e0; e < e1; ++e){
    int s = esrc[e]; if ((unsigned)s >= (unsigned)ns) s = 0;
    float a0 = alpha[(long)e*4 + 0], a1 = alpha[(long)e*4 + 1];
    float a2 = alpha[(long)e*4 + 2], a3 = alpha[(long)e*4 + 3];
    const BF16* ar = A + (long)s*Din;
    if (NJ == 8){
      short8 v = *(const short8*)(ar + lane*8);
      #pragma unroll
      for (int j = 0; j < NJ; ++j){
        float x = bf2f(v[j]);
        acc[0][j] += a0*x; acc[1][j] += a1*x; acc[2][j] += a2*x; acc[3][j] += a3*x;
      }
    } else {
      ushort2 v = *(const ushort2*)(ar + lane*2);
      float x0 = bf2f((short)v.x), x1 = bf2f((short)v.y);
      acc[0][0] += a0*x0; acc[1][0] += a1*x0; acc[2][0] += a2*x0; acc[3][0] += a3*x0;
      acc[0][1] += a0*x1; acc[1][1] += a1*x1; acc[2][1] += a2*x1; acc[3][1] += a3*x1;
    }
  }
  #pragma unroll
  for (int h = 0; h < 4; ++h){
    if (NJ == 8){
      short8 g;
      #pragma unroll
      for (int j = 0; j < NJ; ++j) g[j] = (short)f2bf(acc[h][j]);
      *(short8*)(G + ((long)wid*4 + h)*Din + lane*8) = g;
    } else {
      ushort2 g;
      g.x = f2bf(acc[h][0]); g.y = f2bf(acc[h][1]);
      *(ushort2*)(G + ((long)wid*4 + h)*Din + lane*2) = g;
    }
  }
}

// ---------------- aggregation body (vectorized ushort2 for NJ==2) ---------
template<int NJ>
__device__ __forceinline__ void agg_body(
    const BF16* __restrict__ Zt, const float* __restrict__ alpha,
    const int* __restrict__ indptr, const int* __restrict__ esrc,
    float* acc, int wid, int lane, int TW, int head0, int E, int ns)
{
  int e0 = indptr[wid], e1 = indptr[wid+1];
  e0 = max(0, min(e0, E)); e1 = max(e0, min(e1, E));
  for (int e = e0; e < e1; ++e){
    int s = esrc[e]; if ((unsigned)s >= (unsigned)ns) s = 0;
    float aA = alpha[(long)e*4 + head0];
    const BF16* zr = Zt + (long)s*TW;
    if (NJ == 2){
      ushort2 z = *(const ushort2*)(zr + lane*2);
      acc[0] += aA * bf2f((short)z.x);
      acc[1] += aA * bf2f((short)z.y);
    } else {
      acc[0] += aA * ldE(zr, lane);
    }
  }
}

// ---------------- fused 2-relation aggregation (phase 1, dst=acc) ---------
template<int NJ>
__global__ __launch_bounds__(256) void k_agg2(
    const BF16* __restrict__ Z0, const BF16* __restrict__ Z1,
    const float* __restrict__ a0, const float* __restrict__ a1,
    const int* __restrict__ ip0, const int* __restrict__ ip1,
    const int* __restrict__ es0, const int* __restrict__ es1,
    BF16* __restrict__ out, int ldc, int c0w, int TW, int head0,
    int n_dst, int E, int ns0, int ns1)
{
  int wid = (blockIdx.x*blockDim.x + threadIdx.x) >> 6;
  int lane = threadIdx.x & 63;
  if (wid >= n_dst) return;
  float acc[NJ];
  #pragma unroll
  for (int j = 0; j < NJ; ++j) acc[j] = 0.f;
  agg_body<NJ>(Z0, a0, ip0, es0, acc, wid, lane, TW, head0, E, ns0);
  agg_body<NJ>(Z1, a1, ip1, es1, acc, wid, lane, TW, head0, E, ns1);
  if (NJ == 2){
    ushort2 g; g.x = f2bf(acc[0]); g.y = f2bf(acc[1]);
    *(ushort2*)(out + (long)wid*ldc + c0w + lane*2) = g;
  } else {
    stE(out, (long)wid*ldc + c0w + lane, acc[0]);
  }
}

// ---------------- fused 3-relation aggregation (phase 2, dst=tx) ----------
template<int NJ>
__global__ __launch_bounds__(256) void k_agg3(
    const BF16* __restrict__ Z0, const BF16* __restrict__ Z1, const BF16* __restrict__ Z2,
    const float* __restrict__ a0, const float* __restrict__ a1, const float* __restrict__ a2,
    const int* __restrict__ ip0, const int* __restrict__ ip1, const int* __restrict__ ip2,
    const int* __restrict__ es0, const int* __restrict__ es1, const int* __restrict__ es2,
    BF16* __restrict__ out, int ldc, int TW, int head0,
    int n_dst, int E, int ns0, int ns1, int ns2)
{
  int wid = (blockIdx.x*blockDim.x + threadIdx.x) >> 6;
  int lane = threadIdx.x & 63;
  if (wid >= n_dst) return;
  float acc[NJ];
  #pragma unroll
  for (int j = 0; j < NJ; ++j) acc[j] = 0.f;
  agg_body<NJ>(Z0, a0, ip0, es0, acc, wid, lane, TW, head0, E, ns0);
  agg_body<NJ>(Z1, a1, ip1, es1, acc, wid, lane, TW, head0, E, ns1);
  agg_body<NJ>(Z2, a2, ip2, es2, acc, wid, lane, TW, head0, E, ns2);
  if (NJ == 2){
    ushort2 g; g.x = f2bf(acc[0]); g.y = f2bf(acc[1]);
    *(ushort2*)(out + (long)wid*ldc + lane*2) = g;
  } else {
    stE(out, (long)wid*ldc + lane, acc[0]);
  }
}

// ---------------- BN stats over nw_tile [N, TW] bf16 ----------------------
__global__ void k_bnp(const BF16* __restrict__ nw, float* __restrict__ bnp,
                      int N, int TW, int P)
{
  int col  = threadIdx.x & (TW - 1);
  int slot = threadIdx.x / TW;
  int rpb  = 256 / TW;
  int p    = blockIdx.x*rpb + slot;
  float s = 0.f, s2 = 0.f;
  for (long r = p; r < N; r += P){
    float v = ldE(nw, r*TW + col);
    s += v; s2 += v*v;
  }
  bnp[(long)p*2*TW + col]      = s;
  bnp[(long)p*2*TW + TW + col] = s2;
}
__global__ void k_bnf(const float* __restrict__ bnp, float* __restrict__ bns,
                      int P, int TW)
{
  int c = blockIdx.x*256 + threadIdx.x;
  if (c >= 2*TW) return;
  float s = 0.f;
  for (int p = 0; p < P; ++p) s += bnp[(long)p*2*TW + c];
  bns[c] = s;
}
// ---------------- BN apply (short8, 8 elems/thread) -----------------------
__global__ void k_bn_apply(const BF16* __restrict__ nw, const float* __restrict__ bns,
                           const float* __restrict__ g, const float* __restrict__ b,
                           BF16* __restrict__ A, int N, int TW, int c0, int res)
{
  long total8 = (long)N*TW/8;
  for (long i8 = (long)blockIdx.x*blockDim.x + threadIdx.x; i8 < total8;
       i8 += (long)gridDim.x*blockDim.x){
    long i = i8*8;
    int col = (int)(i % TW);
    long r  = i / TW;
    short8 nv = *(const short8*)(nw + i);
    long ai = r*512 + c0 + col;
    short8 av;
    if (res) av = *(const short8*)(A + ai);
    short8 ov;
    #pragma unroll
    for (int k = 0; k < 8; ++k){
      int gc = c0 + col + k;
      float mu  = bns[col+k] / (float)N;
      float var = bns[TW + col + k] / (float)N - mu*mu;
      float sc = g[gc] * rsqrtf(var + 1e-5f);
      float sh = b[gc] - mu*sc;
      float v = fmaxf(bf2f(nv[k])*sc + sh, 0.f);
      if (res) v += bf2f(av[k]);
      ov[k] = (short)f2bf(v);
    }
    *(short8*)(A + ai) = ov;
  }
}

// ---------------- acc/mer update (short8) ----------------
__global__ void k_update(const BF16* __restrict__ B, const float* __restrict__ ab1,
                         const float* __restrict__ ab2, BF16* __restrict__ A,
                         long n512, int res)
{
  long n8 = n512/8;
  for (long i8 = (long)blockIdx.x*blockDim.x + threadIdx.x; i8 < n8;
       i8 += (long)gridDim.x*blockDim.x){
    long i = i8*8;
    int c = (int)(i & 511);
    short8 bv = *(const short8*)(B + i);
    short8 av;
    if (res) av = *(const short8*)(A + i);
    short8 ov;
    #pragma unroll
    for (int k = 0; k < 8; ++k){
      float v = bf2f(bv[k]) + ab1[c+k] + (ab2 ? ab2[c+k] : 0.f);
      v = fmaxf(v, 0.f);
      if (res) v += bf2f(av[k]);
      ov[k] = (short)f2bf(v);
    }
    *(short8*)(A + i) = ov;
  }
}

// ---------------- head logits ----------------
__global__ void k_logits(const BF16* __restrict__ Hid, const float* __restrict__ Wh2,
                         const float* __restrict__ bh2, float* __restrict__ out, int N)
{
  int node = (blockIdx.x*blockDim.x + threadIdx.x) >> 6;
  int lane = threadIdx.x & 63;
  if (node >= N) return;
  float v = ldE(Hid, (long)node*64 + lane) * Wh2[lane];
  #pragma unroll
  for (int off = 32; off; off >>= 1) v += __shfl_down(v, off, 64);
  if (lane == 0) out[node] = v + bh2[0];
}

// ---------------------------------------------------------------------------
struct Arena {
  BF16 *A[3];
  BF16 *Bst[3];
  BF16 *Zt;
  BF16 *blkB;
  BF16 *hidden;
  float *scoreS, *scoreD;
  float *alpha;
  float *Fbuf;
  float *bnp, *bns;
  int *counts, *bsums;
  int *indptr[6], *esrc[6];
  BF16 *Wt0[6], *WtL[2][6], *Wh1t;
  size_t total;
};

extern "C" void kernel_launch(void* const* d_in, const int* in_sizes, int n_in,
                              void* d_out, int out_size, void* d_ws, size_t ws_size,
                              hipStream_t stream)
{
  const float* x_tx  = (const float*)d_in[0];
  const float* x_acc = (const float*)d_in[1];
  const float* x_mer = (const float*)d_in[2];
  const float* Wtx = (const float*)d_in[3];  const float* btx  = (const float*)d_in[4];
  const float* Wacc= (const float*)d_in[5];  const float* bacc = (const float*)d_in[6];
  const float* Wmer= (const float*)d_in[7];  const float* bmer = (const float*)d_in[8];
  const float* W0   = (const float*)d_in[9];
  const float* Wrest= (const float*)d_in[10];
  const float* att_s= (const float*)d_in[11];
  const float* att_d= (const float*)d_in[12];
  const float* att_b= (const float*)d_in[13];
  const float* bn_g = (const float*)d_in[14];
  const float* bn_b = (const float*)d_in[15];
  const float* Wh1  = (const float*)d_in[16]; const float* bh1 = (const float*)d_in[17];
  const float* Wh2  = (const float*)d_in[18]; const float* bh2 = (const float*)d_in[19];
  const int*   edges= (const int*)d_in[20];

  const int E    = in_sizes[20] / 12;
  const int nTx  = in_sizes[0] / 64;
  const int nAcc = in_sizes[1] / 32;
  const int nMer = in_sizes[2] / 32;
  const int nOf[3]   = {nTx, nAcc, nMer};
  const int SRC_T[6] = {0,0,0,1,1,2};
  const int DST_T[6] = {1,1,2,0,0,0};
  const int maxN = max(nTx, max(nAcc, nMer));
  (void)n_in;

  auto layout = [&](int TW)->Arena{
    Arena P{};
    size_t off = 0;
    auto a = [&](size_t bytes)->char*{
      char* p = (char*)d_ws + off;
      off += (bytes + 255) & ~(size_t)255;
      return p;
    };
    auto al = [](size_t b){ return (b + 255) & ~(size_t)255; };
    P.A[0]   = (BF16*)a((size_t)nTx *512*2);
    P.A[1]   = (BF16*)a((size_t)nAcc*512*2);
    P.A[2]   = (BF16*)a((size_t)nMer*512*2);
    P.Bst[1] = (BF16*)a((size_t)nAcc*512*2);
    P.Bst[2] = (BF16*)a((size_t)nMer*512*2);
    size_t zrowsA = (size_t)maxN > (size_t)2*nAcc + nMer ? (size_t)maxN : (size_t)2*nAcc + nMer;
    size_t blkA = al(zrowsA*TW*2);
    size_t blkBsz = al((size_t)nTx*TW*2);
    size_t gB = al((size_t)nMer*4*512*2);
    if (gB > blkBsz) blkBsz = gB;
    size_t scoreB = al((size_t)3*maxN*4*4)*2;
    size_t hidB = al((size_t)nTx*64*2);
    size_t scr = blkA + blkBsz;
    if (scr < scoreB) scr = scoreB;
    if (scr < hidB)   scr = hidB;
    char* scrBase = a(scr);
    P.Zt     = (BF16*)scrBase;
    P.blkB   = (BF16*)(scrBase + blkA);
    P.scoreS = (float*)scrBase;
    P.scoreD = (float*)(scrBase + al((size_t)3*maxN*4*4));
    P.hidden = (BF16*)scrBase;
    P.alpha  = (float*)a((size_t)3*E*4*4);
    P.Fbuf   = (float*)a((size_t)6*8*512*4);
    P.bnp    = (float*)a(262144);
    P.bns    = (float*)a(4096);
    P.counts = (int*)a((size_t)maxN*4);
    P.bsums  = (int*)a(4096);
    for (int r = 0; r < 6; ++r){
      P.indptr[r] = (int*)a((size_t)(nOf[DST_T[r]]+1)*4);
      P.esrc[r]   = (int*)a((size_t)E*4);
    }
    for (int r = 0; r < 6; ++r) P.Wt0[r] = (BF16*)a((size_t)512*128*2);
    for (int l = 0; l < 2; ++l)
      for (int r = 0; r < 6; ++r) P.WtL[l][r] = (BF16*)a((size_t)512*512*2);
    P.Wh1t = (BF16*)a((size_t)64*512*2);
    P.total = off;
    return P;
  };

  int TW = 0;
  Arena P{};
  for (int cand : {128, 64}){
    P = layout(cand);
    if (P.total <= ws_size){ TW = cand; break; }
  }
  if (TW == 0){
    float sentinel = 10000.0f + (float)(ws_size >> 20);
    k_fill_f32<<<dim3((out_size+255)/256), dim3(256), 0, stream>>>((float*)d_out, (long)out_size, sentinel);
    return;
  }
  const int nTiles = 512 / TW;
  const int NJv = TW/64;
  const int rpb = 256 / TW, PBX = 64, Pp = PBX * rpb;
  dim3 b256(256);

  // ---- 0. weight prep (3 batched launches) ----
  k_wt<<<dim3(16,4,6),  b256, 0, stream>>>(W0,    P.Wt0[0],    128, 512);
  k_wt<<<dim3(16,16,12),b256, 0, stream>>>(Wrest, P.WtL[0][0], 512, 512);
  k_wt<<<dim3(2,16,1),  b256, 0, stream>>>(Wh1,   P.Wh1t,      512, 64);

  auto mfma_gemm = [&](const BF16* A, const BF16* Bt, BF16* Cp, int M, int K, int c0, int ldc){
    if (TW >= 128)
      k_mfma<128,2,2,4,4,BF16><<<dim3(TW/128,(M+127)/128,1),b256,0,stream>>>(
          A, Bt, Cp, M, K, c0, ldc, K, (const float*)nullptr, 0, 0, 0L, 0L, 0, (const BF16*)nullptr);
    else
      k_mfma<64,4,1,2,4,BF16><<<dim3(1,(M+127)/128,1),b256,0,stream>>>(
          A, Bt, Cp, M, K, c0, ldc, K, (const float*)nullptr, 0, 0, 0L, 0L, 0, (const BF16*)nullptr);
  };
  auto mfma_pair = [&](const BF16* A, const BF16* Bt0, const BF16* Bt1p, BF16* Cp, long cZst,
                       int M, int K, int c0){
    if (TW >= 128)
      k_mfma<128,2,2,4,4,BF16><<<dim3(TW/128,(M+127)/128,2),b256,0,stream>>>(
          A, Bt0, Cp, M, K, c0, TW, K, (const float*)nullptr, 0, 0, 0L, cZst, 0, Bt1p);
    else {
      mfma_gemm(A, Bt0, Cp, M, K, c0, TW);
      mfma_gemm(A, Bt1p, Cp + cZst, M, K, c0, TW);
    }
  };

  // ---- 1. CSR build (per-relation) ----
  for (int r = 0; r < 6; ++r){
    int nd = nOf[DST_T[r]], ns = nOf[SRC_T[r]];
    const int* srcP = edges + (size_t)r*2*E;
    const int* dstP = srcP + E;
    int nb = (nd + 255)/256;
    k_zero   <<<dim3(nb),          b256, 0, stream>>>(P.counts, (long)nd);
    k_hist   <<<dim3((E+255)/256), b256, 0, stream>>>(dstP, P.counts, E, nd);
    k_scan1  <<<dim3(nb),          b256, 0, stream>>>(P.counts, P.indptr[r], P.bsums, nd);
    k_scan2  <<<dim3(1),           dim3(1024),0, stream>>>(P.bsums, nb);
    k_scan3  <<<dim3(nb),          b256, 0, stream>>>(P.indptr[r], P.bsums, nd);
    k_zero   <<<dim3(nb),          b256, 0, stream>>>(P.counts, (long)nd);
    k_scatter<<<dim3((E+255)/256), b256, 0, stream>>>(srcP, dstP, P.indptr[r], P.counts, P.esrc[r], E, nd, ns);
  }

  // ---- 2. encoders ----
  k_gemm<float,BF16><<<dim3(2,(nTx +63)/64), b256, 0, stream>>>(x_tx,  Wtx,  P.A[0], nTx,  128, 64, 128, btx,  1);
  k_gemm<float,BF16><<<dim3(2,(nAcc+63)/64), b256, 0, stream>>>(x_acc, Wacc, P.A[1], nAcc, 128, 32, 128, bacc, 1);
  k_gemm<float,BF16><<<dim3(2,(nMer+63)/64), b256, 0, stream>>>(x_mer, Wmer, P.A[2], nMer, 128, 32, 128, bmer, 1);

  const long mS = (long)maxN*4;
  // ---- 3. layers ----
  for (int i = 0; i < 3; ++i){
    const int Din = (i == 0) ? 128 : 512;
    const int res = (i > 0) ? 1 : 0;
    const long fstr = 8L*Din;
    const float* WbaseL = (i == 0) ? W0 : (Wrest + (size_t)(i-1)*6*512*512);
    const long wstride = (i == 0) ? 128L*512 : 512L*512;
    auto Wtof = [&](int r)->const BF16*{ return (i == 0) ? P.Wt0[r] : P.WtL[i-1][r]; };

    k_foldAll<<<dim3(48*Din/4), b256, 0, stream>>>(WbaseL, wstride,
        att_s + (size_t)i*6*512, att_d + (size_t)i*6*512, P.Fbuf, Din);

    // ---- Phase 1: scores, then ALL alphas (batched) ----
    k_scoreM<3><<<dim3((nTx+15)/16), b256, 0, stream>>>(P.A[0], P.Fbuf,           fstr, P.scoreS, mS, nTx, Din);
    k_scoreM<2><<<dim3((nAcc+15)/16), b256, 0, stream>>>(P.A[1], P.Fbuf + 4*Din,  fstr, P.scoreD, mS, nAcc, Din);
    k_scoreM<1><<<dim3((nMer+15)/16), b256, 0, stream>>>(P.A[2], P.Fbuf + 20*Din, fstr, P.scoreD + 2*mS, 0, nMer, Din);
    {
      AlphaArgs aa{};
      int ndMax = 0;
      for (int r = 0; r < 3; ++r){
        aa.ss[r] = P.scoreS + r*mS; aa.sd[r] = P.scoreD + r*mS;
        aa.ip[r] = P.indptr[r]; aa.es[r] = P.esrc[r];
        aa.al[r] = P.alpha + (size_t)r*E*4;
        aa.nd[r] = nOf[DST_T[r]]; aa.ns[r] = nTx;
        if (aa.nd[r] > ndMax) ndMax = aa.nd[r];
      }
      k_alpha3b<<<dim3((ndMax+3)/4,3), b256, 0, stream>>>(aa, E);
    }
    // r=2 (tx->mer): aggregate-FIRST; 4 head-GEMMs in one z=4 launch
    {
      BF16* Gm = P.blkB;
      if (Din == 512)
        k_gather4<8><<<dim3((nMer+3)/4), b256, 0, stream>>>(P.A[0], P.alpha + (size_t)2*E*4,
            P.indptr[2], P.esrc[2], Gm, nMer, Din, E, nTx);
      else
        k_gather4<2><<<dim3((nMer+3)/4), b256, 0, stream>>>(P.A[0], P.alpha + (size_t)2*E*4,
            P.indptr[2], P.esrc[2], Gm, nMer, Din, E, nTx);
      k_mfma<128,2,2,4,4,BF16><<<dim3(1,(nMer+127)/128,4), b256, 0, stream>>>(
          Gm, Wtof(2), P.Bst[2], nMer, Din, 0, 512, 4*Din,
          (const float*)nullptr, 0, 0, (long)Din, 128L, 128, (const BF16*)nullptr);
    }
    // r=0,1 (tx->acc): z=2 pair GEMM + fused agg2
    {
      BF16* Zr0 = P.Zt;
      BF16* Zr1 = P.blkB;
      long zst = (long)(Zr1 - Zr0);
      for (int t = 0; t < nTiles; ++t){
        int c0 = t*TW;
        mfma_pair(P.A[0], Wtof(0), Wtof(1), Zr0, zst, nTx, Din, c0);
        dim3 ga((nAcc+3)/4);
        if (NJv == 2)
          k_agg2<2><<<ga,b256,0,stream>>>(Zr0, Zr1, P.alpha, P.alpha + (size_t)E*4,
              P.indptr[0], P.indptr[1], P.esrc[0], P.esrc[1],
              P.Bst[1], 512, c0, TW, c0>>7, nAcc, E, nTx, nTx);
        else
          k_agg2<1><<<ga,b256,0,stream>>>(Zr0, Zr1, P.alpha, P.alpha + (size_t)E*4,
              P.indptr[0], P.indptr[1], P.esrc[0], P.esrc[1],
              P.Bst[1], 512, c0, TW, c0>>7, nAcc, E, nTx, nTx);
      }
    }

    // ---- Phase 2 (dst=tx; src=acc r=3,4; mer r=5) ----
    k_scoreM<2><<<dim3((nAcc+15)/16), b256, 0, stream>>>(P.A[1], P.Fbuf + 24*Din, fstr, P.scoreS, mS, nAcc, Din);
    k_scoreM<1><<<dim3((nMer+15)/16), b256, 0, stream>>>(P.A[2], P.Fbuf + 40*Din, fstr, P.scoreS + 2*mS, 0, nMer, Din);
    k_scoreM<3><<<dim3((nTx+15)/16), b256, 0, stream>>>(P.A[0], P.Fbuf + 28*Din, fstr, P.scoreD, mS, nTx, Din);
    {
      AlphaArgs aa{};
      for (int q = 0; q < 3; ++q){
        int r = 3 + q;
        aa.ss[q] = P.scoreS + q*mS; aa.sd[q] = P.scoreD + q*mS;
        aa.ip[q] = P.indptr[r]; aa.es[q] = P.esrc[r];
        aa.al[q] = P.alpha + (size_t)q*E*4;
        aa.nd[q] = nTx; aa.ns[q] = nOf[SRC_T[r]];
      }
      k_alpha3b<<<dim3((nTx+3)/4,3), b256, 0, stream>>>(aa, E);
    }
    BF16* Z3 = P.Zt;
    BF16* Z4 = P.Zt + (size_t)nAcc*TW;
    BF16* Z5 = P.Zt + (size_t)2*nAcc*TW;
    BF16* nw = P.blkB;
    for (int t = 0; t < nTiles; ++t){
      int c0 = t*TW;
      mfma_pair(P.A[1], Wtof(3), Wtof(4), Z3, (long)nAcc*TW, nAcc, Din, c0);
      mfma_gemm(P.A[2], Wtof(5), Z5, nMer, Din, c0, TW);
      dim3 ga((nTx+3)/4);
      if (NJv == 2)
        k_agg3<2><<<ga,b256,0,stream>>>(Z3,Z4,Z5, P.alpha, P.alpha+(size_t)E*4, P.alpha+(size_t)2*E*4,
            P.indptr[3],P.indptr[4],P.indptr[5], P.esrc[3],P.esrc[4],P.esrc[5],
            nw, TW, TW, c0>>7, nTx, E, nAcc, nAcc, nMer);
      else
        k_agg3<1><<<ga,b256,0,stream>>>(Z3,Z4,Z5, P.alpha, P.alpha+(size_t)E*4, P.alpha+(size_t)2*E*4,
            P.indptr[3],P.indptr[4],P.indptr[5], P.esrc[3],P.esrc[4],P.esrc[5],
            nw, TW, TW, c0>>7, nTx, E, nAcc, nAcc, nMer);
      k_bnp<<<dim3(PBX), b256, 0, stream>>>(nw, P.bnp, nTx, TW, Pp);
      k_bnf<<<dim3((2*TW+255)/256), b256, 0, stream>>>(P.bnp, P.bns, Pp, TW);
      k_bn_apply<<<dim3(2048), b256, 0, stream>>>(nw, P.bns,
          bn_g + (size_t)i*512, bn_b + (size_t)i*512, P.A[0], nTx, TW, c0, res);
    }
    // ---- Phase 3 ----
    const float* ab0 = att_b + ((size_t)(i*6 + 0))*512;
    const float* ab1 = att_b + ((size_t)(i*6 + 1))*512;
    const float* ab2 = att_b + ((size_t)(i*6 + 2))*512;
    k_update<<<dim3(1024), b256, 0, stream>>>(P.Bst[1], ab0, ab1, P.A[1], (long)nAcc*512, res);
    k_update<<<dim3(128),  b256, 0, stream>>>(P.Bst[2], ab2, (const float*)nullptr, P.A[2], (long)nMer*512, res);
  }

  // ---- 4. head ----
  k_mfma<64,4,1,2,4,BF16><<<dim3(1,(nTx+127)/128,1), b256, 0, stream>>>(
      P.A[0], P.Wh1t, P.hidden, nTx, 512, 0, 64, 512, bh1, 1, 0,
      0L, 0L, 0, (const BF16*)nullptr);
  k_logits<<<dim3((nTx+3)/4), b256, 0, stream>>>(P.hidden, Wh2, bh2, (float*)d_out, nTx);
}

// Round 20
// 10121.456 us; speedup vs baseline: 1.8047x; 1.0003x over previous
//
#include <hip/hip_runtime.h>
#include <math.h>

// ---------------------------------------------------------------------------
// FraudGAT: bf16 storage, MFMA projections, pre-transposed bf16 weights.
// R20 = R19 + k_mfma2: 512-thread 128x256-tile GEMM for the two "pair" sites
// (phase1 r0/r1, phase2 Z3/Z4). One block stages the A tile ONCE and computes
// both weight matrices' outputs (B rows 0-127 from Bt0, 128-255 from Bt1).
// Arena byte-identical to R19 (TW=128 tier verified; ws in [284.25,285) MB).
// ---------------------------------------------------------------------------

typedef unsigned short BF16;
typedef short short8 __attribute__((ext_vector_type(8)));
typedef float f32x4 __attribute__((ext_vector_type(4)));
typedef __bf16 bf16x8 __attribute__((ext_vector_type(8)));

static __device__ __forceinline__ float lrelu(float x){ return x > 0.f ? x : 0.2f*x; }

__device__ __forceinline__ float ldE(const float* p, long i){ return p[i]; }
__device__ __forceinline__ float ldE(const BF16* p, long i){
  return __uint_as_float((unsigned)p[i] << 16);
}
__device__ __forceinline__ void stE(float* p, long i, float v){ p[i] = v; }
__device__ __forceinline__ void stE(BF16* p, long i, float v){
  unsigned u = __float_as_uint(v);
  p[i] = (BF16)((u + 0x7FFFu + ((u >> 16) & 1u)) >> 16);
}
__device__ __forceinline__ BF16 f2bf(float v){
  unsigned u = __float_as_uint(v);
  return (BF16)((u + 0x7FFFu + ((u >> 16) & 1u)) >> 16);
}
__device__ __forceinline__ float bf2f(short s){
  return __uint_as_float((unsigned)(unsigned short)s << 16);
}
__device__ __forceinline__ float4 ld4E(const float* p, long i){ return *(const float4*)(p + i); }
__device__ __forceinline__ float4 ld4E(const BF16* p, long i){
  ushort4 s = *(const ushort4*)(p + i);
  return make_float4(__uint_as_float((unsigned)s.x<<16), __uint_as_float((unsigned)s.y<<16),
                     __uint_as_float((unsigned)s.z<<16), __uint_as_float((unsigned)s.w<<16));
}

// ---------------- utility ----------------
__global__ void k_zero(int* __restrict__ p, long n){
  long i = (long)blockIdx.x*blockDim.x + threadIdx.x;
  if (i < n) p[i] = 0;
}
__global__ void k_fill_f32(float* __restrict__ p, long n, float v){
  long i = (long)blockIdx.x*blockDim.x + threadIdx.x;
  if (i < n) p[i] = v;
}

// ---------------- weight transpose+convert (z-batched) --------------------
__global__ __launch_bounds__(256) void k_wt(const float* __restrict__ in, BF16* __restrict__ out,
                                            int K, int N)
{
  in  += (long)blockIdx.z*K*N;
  out += (long)blockIdx.z*N*K;
  __shared__ float t[32][33];
  int kb = blockIdx.y*32, nb = blockIdx.x*32;
  int tx = threadIdx.x & 31, ty8 = threadIdx.x >> 5;
  for (int j = ty8; j < 32; j += 8){
    int k = kb + j, n = nb + tx;
    t[j][tx] = (k < K && n < N) ? in[(long)k*N + n] : 0.f;
  }
  __syncthreads();
  for (int j = ty8; j < 32; j += 8){
    int n = nb + j, k = kb + tx;
    if (n < N && k < K) out[(long)n*K + k] = f2bf(t[tx][j]);
  }
}

// ---------------- fold ALL 12 tables in one launch ------------------------
__global__ __launch_bounds__(256) void k_foldAll(
    const float* __restrict__ Wbase, long wstride,
    const float* __restrict__ atts, const float* __restrict__ attd,
    float* __restrict__ F, int Din)
{
  int w = (blockIdx.x*256 + threadIdx.x) >> 6;
  int lane = threadIdx.x & 63;
  int total = 48*Din;
  if (w >= total) return;
  int k = w % Din;
  int rem = w / Din;
  int h = rem & 3, sd = (rem >> 2) & 1, r = rem >> 3;
  const float* wr = Wbase + (long)r*wstride + (long)k*512 + h*128;
  const float* ar = (sd ? attd : atts) + r*512 + h*128;
  float p = wr[lane]*ar[lane] + wr[lane+64]*ar[lane+64];
  #pragma unroll
  for (int off = 32; off; off >>= 1) p += __shfl_down(p, off, 64);
  if (lane == 0) F[(long)((r*2+sd)*4 + h)*Din + k] = p;
}

// ---------------- MFMA GEMM (reg staging, LSTR=72 pad; optionally z-batched)
template<int BN, int WM, int WN, int FM, int FN, typename TC>
__global__ __launch_bounds__(256) void k_mfma(
    const BF16* __restrict__ A, const BF16* __restrict__ Bt, TC* __restrict__ C,
    int M, int K, int c0, int ldc, int lda, const float* __restrict__ bias,
    int doRelu, int accum, long aZst, long cZst, int c0Zst, const BF16* __restrict__ Bt1)
{
  constexpr int BM = 128;
  constexpr int LSTR = 72;
  __shared__ __attribute__((aligned(16))) short Als[BM][LSTR];
  __shared__ __attribute__((aligned(16))) short Bls[BN][LSTR];
  const int z = blockIdx.z;
  A += (long)z*aZst;
  C += (long)z*cZst;
  c0 += z*c0Zst;
  if (z >= 1 && Bt1) Bt = Bt1;
  const int bn0 = blockIdx.x * BN;
  const int bm = blockIdx.y*BM;
  const int tid = threadIdx.x;
  const int wave = tid >> 6, lane = tid & 63;
  const int wr = wave / WN, wc = wave % WN;
  const int lrow = lane & 15, kg = lane >> 4;
  f32x4 acc[FM][FN] = {};
  for (int k0 = 0; k0 < K; k0 += 64){
    #pragma unroll
    for (int t = 0; t < 4; ++t){
      int idx = tid + t*256;
      int row = idx >> 3, kc = (idx & 7) << 3;
      int gr = bm + row;
      short8 v = {};
      if (gr < M) v = *(const short8*)(A + (long)gr*lda + k0 + kc);
      *(short8*)&Als[row][kc] = v;
    }
    #pragma unroll
    for (int t = 0; t < BN/32; ++t){
      int idx = tid + t*256;
      int row = idx >> 3, kc = (idx & 7) << 3;
      *(short8*)&Bls[row][kc] = *(const short8*)(Bt + (long)(c0+bn0+row)*K + k0 + kc);
    }
    __syncthreads();
    #pragma unroll
    for (int kk = 0; kk < 2; ++kk){
      short8 af[FM], bq[FN];
      #pragma unroll
      for (int m = 0; m < FM; ++m)
        af[m] = *(const short8*)&Als[wr*FM*16 + m*16 + lrow][kk*32 + kg*8];
      #pragma unroll
      for (int n = 0; n < FN; ++n)
        bq[n] = *(const short8*)&Bls[wc*FN*16 + n*16 + lrow][kk*32 + kg*8];
      #pragma unroll
      for (int m = 0; m < FM; ++m)
        #pragma unroll
        for (int n = 0; n < FN; ++n)
          acc[m][n] = __builtin_amdgcn_mfma_f32_16x16x32_bf16(
              __builtin_bit_cast(bf16x8, af[m]), __builtin_bit_cast(bf16x8, bq[n]),
              acc[m][n], 0, 0, 0);
    }
    __syncthreads();
  }
  // epilogue: C/D layout col=lane&15, row=(lane>>4)*4+reg  [m89]
  #pragma unroll
  for (int m = 0; m < FM; ++m){
    #pragma unroll
    for (int n = 0; n < FN; ++n){
      #pragma unroll
      for (int j = 0; j < 4; ++j){
        int row = bm + wr*FM*16 + m*16 + kg*4 + j;
        if (row >= M) continue;
        int col = wc*FN*16 + n*16 + lrow;
        float v = acc[m][n][j];
        if (bias) v += bias[bn0 + col];
        if (doRelu) v = fmaxf(v, 0.f);
        long idx = (long)row*ldc + bn0 + col;
        if (accum) v += ldE(C, idx);
        stE(C, idx, v);
      }
    }
  }
}

// ---------------- PAIR MFMA GEMM: 512 thr, 128x256 tile, two B matrices ---
// C0[:, 0:128) = A @ Bt0[c0..c0+128)^T ; C1 likewise with Bt1. ldc = 128.
// One block stages A ONCE for both outputs. K%64==0.
__global__ __launch_bounds__(512) void k_mfma2(
    const BF16* __restrict__ A, const BF16* __restrict__ Bt0, const BF16* __restrict__ Bt1,
    BF16* __restrict__ C0, BF16* __restrict__ C1,
    int M, int K, int c0, int ldc, int lda)
{
  constexpr int BM = 128, BN = 256, LSTR = 72;
  __shared__ __attribute__((aligned(16))) short Als[BM][LSTR];
  __shared__ __attribute__((aligned(16))) short Bls[BN][LSTR];
  const int bm = blockIdx.y*BM;
  const int tid = threadIdx.x;              // 0..511
  const int wave = tid >> 6, lane = tid & 63;
  const int wr = wave >> 2, wc = wave & 3;  // 2 x 4 wave grid (64x64 each)
  const int lrow = lane & 15, kg = lane >> 4;
  f32x4 acc[4][4] = {};
  for (int k0 = 0; k0 < K; k0 += 64){
    // stage A [128][64]: 1024 chunks of 8, 512 threads x 2
    #pragma unroll
    for (int t = 0; t < 2; ++t){
      int idx = tid + t*512;
      int row = idx >> 3, kc = (idx & 7) << 3;
      int gr = bm + row;
      short8 v = {};
      if (gr < M) v = *(const short8*)(A + (long)gr*lda + k0 + kc);
      *(short8*)&Als[row][kc] = v;
    }
    // stage B [256][64]: rows 0-127 from Bt0, 128-255 from Bt1
    #pragma unroll
    for (int t = 0; t < 4; ++t){
      int idx = tid + t*512;
      int row = idx >> 3, kc = (idx & 7) << 3;
      const BF16* src = (row < 128) ? (Bt0 + (long)(c0 + row)*K)
                                    : (Bt1 + (long)(c0 + row - 128)*K);
      *(short8*)&Bls[row][kc] = *(const short8*)(src + k0 + kc);
    }
    __syncthreads();
    #pragma unroll
    for (int kk = 0; kk < 2; ++kk){
      short8 af[4], bq[4];
      #pragma unroll
      for (int m = 0; m < 4; ++m)
        af[m] = *(const short8*)&Als[wr*64 + m*16 + lrow][kk*32 + kg*8];
      #pragma unroll
      for (int n = 0; n < 4; ++n)
        bq[n] = *(const short8*)&Bls[wc*64 + n*16 + lrow][kk*32 + kg*8];
      #pragma unroll
      for (int m = 0; m < 4; ++m)
        #pragma unroll
        for (int n = 0; n < 4; ++n)
          acc[m][n] = __builtin_amdgcn_mfma_f32_16x16x32_bf16(
              __builtin_bit_cast(bf16x8, af[m]), __builtin_bit_cast(bf16x8, bq[n]),
              acc[m][n], 0, 0, 0);
    }
    __syncthreads();
  }
  // epilogue: col in [0,256): <128 -> C0, else C1 (C/D layout per m89)
  #pragma unroll
  for (int m = 0; m < 4; ++m){
    #pragma unroll
    for (int n = 0; n < 4; ++n){
      #pragma unroll
      for (int j = 0; j < 4; ++j){
        int row = bm + wr*64 + m*16 + kg*4 + j;
        if (row >= M) continue;
        int col = wc*64 + n*16 + lrow;
        BF16* C = (col < 128) ? C0 : C1;
        int cc = (col < 128) ? col : col - 128;
        stE(C, (long)row*ldc + cc, acc[m][n][j]);
      }
    }
  }
}

// ---------------- naive GEMM (f32 A) for the tiny encoders ----------------
template<typename TA, typename TC>
__global__ __launch_bounds__(256) void k_gemm(
    const TA* __restrict__ A, const float* __restrict__ B, TC* __restrict__ C,
    int M, int N, int K, int ldb, const float* __restrict__ bias, int doRelu)
{
  __shared__ float As[16][64];
  __shared__ float Bs[16][64];
  const int bm = blockIdx.y*64, bn = blockIdx.x*64;
  const int tid = threadIdx.x;
  const int ty = tid >> 4, tx = tid & 15;
  const int ar = tid >> 2;
  const int ac = (tid & 3) << 2;
  const int br = tid >> 4;
  const int bc = (tid & 15) << 2;
  float acc[4][4] = {};
  for (int k0 = 0; k0 < K; k0 += 16){
    int row = bm + ar;
    float4 av = make_float4(0.f,0.f,0.f,0.f);
    if (row < M) av = ld4E(A, (long)row*K + k0 + ac);
    As[ac+0][ar]=av.x; As[ac+1][ar]=av.y; As[ac+2][ar]=av.z; As[ac+3][ar]=av.w;
    float4 bv = make_float4(0.f,0.f,0.f,0.f);
    if (bn + bc + 3 < N) bv = *(const float4*)(B + (long)(k0+br)*ldb + bn + bc);
    *(float4*)&Bs[br][bc] = bv;
    __syncthreads();
    #pragma unroll
    for (int kk = 0; kk < 16; ++kk){
      float a[4], b[4];
      #pragma unroll
      for (int x = 0; x < 4; ++x){ a[x]=As[kk][ty*4+x]; b[x]=Bs[kk][tx*4+x]; }
      #pragma unroll
      for (int y = 0; y < 4; ++y)
        #pragma unroll
        for (int x = 0; x < 4; ++x) acc[y][x] += a[y]*b[x];
    }
    __syncthreads();
  }
  #pragma unroll
  for (int y = 0; y < 4; ++y){
    int row = bm + ty*4 + y;
    if (row >= M) continue;
    #pragma unroll
    for (int x = 0; x < 4; ++x){
      int col = bn + tx*4 + x;
      if (col >= N) continue;
      float v = acc[y][x];
      if (bias) v += bias[col];
      if (doRelu) v = fmaxf(v, 0.f);
      stE(C, (long)row*N + col, v);
    }
  }
}

// ---------------- merged scores: R relations, one pass over X -------------
template<int R>
__global__ __launch_bounds__(256) void k_scoreM(
    const BF16* __restrict__ X, const float* __restrict__ Ftab, long fstride,
    float* __restrict__ out, long ostride, int N, int Din)
{
  int wave = threadIdx.x >> 6, lane = threadIdx.x & 63;
  int node0 = blockIdx.x*16 + wave*4;
  if (node0 >= N) return;
  int base = lane*8;
  bool act = base < Din;
  float x[4][8];
  #pragma unroll
  for (int t = 0; t < 4; ++t){
    int node = node0 + t;
    if (act && node < N){
      short8 v = *(const short8*)(X + (long)node*Din + base);
      #pragma unroll
      for (int j = 0; j < 8; ++j) x[t][j] = bf2f(v[j]);
    } else {
      #pragma unroll
      for (int j = 0; j < 8; ++j) x[t][j] = 0.f;
    }
  }
  #pragma unroll
  for (int r = 0; r < R; ++r){
    const float* F = Ftab + (long)r*fstride;
    float p[4][4] = {};
    #pragma unroll
    for (int h = 0; h < 4; ++h){
      float f[8];
      if (act){
        float4 fa = *(const float4*)(F + h*Din + base);
        float4 fb = *(const float4*)(F + h*Din + base + 4);
        f[0]=fa.x; f[1]=fa.y; f[2]=fa.z; f[3]=fa.w;
        f[4]=fb.x; f[5]=fb.y; f[6]=fb.z; f[7]=fb.w;
      } else {
        #pragma unroll
        for (int j = 0; j < 8; ++j) f[j] = 0.f;
      }
      #pragma unroll
      for (int t = 0; t < 4; ++t)
        #pragma unroll
        for (int j = 0; j < 8; ++j) p[t][h] += x[t][j]*f[j];
    }
    #pragma unroll
    for (int t = 0; t < 4; ++t)
      #pragma unroll
      for (int h = 0; h < 4; ++h)
        #pragma unroll
        for (int off = 32; off; off >>= 1)
          p[t][h] += __shfl_down(p[t][h], off, 64);
    if (lane == 0){
      #pragma unroll
      for (int t = 0; t < 4; ++t){
        int node = node0 + t;
        if (node < N){
          #pragma unroll
          for (int h = 0; h < 4; ++h)
            out[(long)r*ostride + (long)node*4 + h] = p[t][h];
        }
      }
    }
  }
}

// ---------------- CSR build (per-relation) --------------------------------
__global__ void k_hist(const int* __restrict__ dst, int* __restrict__ counts, int E, int nd){
  int e = blockIdx.x*blockDim.x + threadIdx.x;
  if (e >= E) return;
  int d = dst[e];
  if ((unsigned)d < (unsigned)nd) atomicAdd(&counts[d], 1);
}
__global__ void k_scan1(const int* __restrict__ counts, int* __restrict__ indptr,
                        int* __restrict__ bsums, int n)
{
  __shared__ int sm[256];
  int i = blockIdx.x*256 + threadIdx.x;
  int v = (i < n) ? counts[i] : 0;
  sm[threadIdx.x] = v; __syncthreads();
  for (int off = 1; off < 256; off <<= 1){
    int t = (threadIdx.x >= off) ? sm[threadIdx.x - off] : 0;
    __syncthreads();
    sm[threadIdx.x] += t;
    __syncthreads();
  }
  if (i < n) indptr[i+1] = sm[threadIdx.x];
  if (threadIdx.x == 255) bsums[blockIdx.x] = sm[255];
  if (blockIdx.x == 0 && threadIdx.x == 0) indptr[0] = 0;
}
__global__ void k_scan2(int* __restrict__ bsums, int nb){
  __shared__ int sm[1024];
  int t = threadIdx.x;
  int v = (t < nb) ? bsums[t] : 0;
  sm[t] = v; __syncthreads();
  for (int off = 1; off < 1024; off <<= 1){
    int x = (t >= off) ? sm[t - off] : 0;
    __syncthreads();
    sm[t] += x;
    __syncthreads();
  }
  if (t < nb) bsums[t] = sm[t];
}
__global__ void k_scan3(int* __restrict__ indptr, const int* __restrict__ bsums, int n){
  if (blockIdx.x == 0) return;
  int i = blockIdx.x*256 + threadIdx.x;
  int add = bsums[blockIdx.x - 1];
  if (i < n) indptr[i+1] += add;
}
__global__ void k_scatter(const int* __restrict__ src, const int* __restrict__ dst,
                          const int* __restrict__ indptr, int* __restrict__ cursor,
                          int* __restrict__ esrc, int E, int nd, int ns)
{
  int e = blockIdx.x*blockDim.x + threadIdx.x;
  if (e >= E) return;
  int d = dst[e];
  if ((unsigned)d >= (unsigned)nd) return;
  int s = src[e];
  if ((unsigned)s >= (unsigned)ns) s = 0;
  int pos = indptr[d] + atomicAdd(&cursor[d], 1);
  if (pos >= 0 && pos < E) esrc[pos] = s;
}

// ---------------- batched per-edge alpha (3 relations, grid.y) ------------
struct AlphaArgs {
  const float* ss[3]; const float* sd[3];
  const int* ip[3]; const int* es[3];
  float* al[3]; int nd[3]; int ns[3];
};
__global__ __launch_bounds__(256) void k_alpha3b(AlphaArgs a, int E){
  int r = blockIdx.y;
  int wid = (blockIdx.x*blockDim.x + threadIdx.x) >> 6;
  int lane = threadIdx.x & 63;
  if (wid >= a.nd[r]) return;
  const int* indptr = a.ip[r];
  const int* esrc = a.es[r];
  const float* ss = a.ss[r];
  int ns = a.ns[r];
  int e0 = indptr[wid], e1 = indptr[wid+1];
  e0 = max(0, min(e0, E)); e1 = max(e0, min(e1, E));
  if (e0 >= e1) return;
  int h = lane >> 4, g = lane & 15;
  float sdl = a.sd[r][(long)wid*4 + h];
  float* alpha = a.al[r];
  float m = -INFINITY;
  for (int e = e0 + g; e < e1; e += 16){
    int s = esrc[e]; if ((unsigned)s >= (unsigned)ns) s = 0;
    m = fmaxf(m, lrelu(ss[(long)s*4 + h] + sdl));
  }
  #pragma unroll
  for (int o = 1; o < 16; o <<= 1) m = fmaxf(m, __shfl_xor(m, o, 16));
  float den = 0.f;
  for (int e = e0 + g; e < e1; e += 16){
    int s = esrc[e]; if ((unsigned)s >= (unsigned)ns) s = 0;
    den += __expf(lrelu(ss[(long)s*4 + h] + sdl) - m);
  }
  #pragma unroll
  for (int o = 1; o < 16; o <<= 1) den += __shfl_xor(den, o, 16);
  float inv = 1.f/(den + 1e-16f);
  for (int e = e0 + g; e < e1; e += 16){
    int s = esrc[e]; if ((unsigned)s >= (unsigned)ns) s = 0;
    alpha[(long)e*4 + h] = __expf(lrelu(ss[(long)s*4 + h] + sdl) - m) * inv;
  }
}

// ---------------- aggregate-FIRST gather (r=2, all 4 heads, vectorized) ---
template<int NJ>
__global__ __launch_bounds__(256) void k_gather4(
    const BF16* __restrict__ A, const float* __restrict__ alpha,
    const int* __restrict__ indptr, const int* __restrict__ esrc,
    BF16* __restrict__ G, int n_dst, int Din, int E, int ns)
{
  int wid = (blockIdx.x*blockDim.x + threadIdx.x) >> 6;
  int lane = threadIdx.x & 63;
  if (wid >= n_dst) return;
  int e0 = indptr[wid], e1 = indptr[wid+1];
  e0 = max(0, min(e0, E)); e1 = max(e0, min(e1, E));
  float acc[4][NJ];
  #pragma unroll
  for (int h = 0; h < 4; ++h)
    #pragma unroll
    for (int j = 0; j < NJ; ++j) acc[h][j] = 0.f;
  for (int e = e0; e < e1; ++e){
    int s = esrc[e]; if ((unsigned)s >= (unsigned)ns) s = 0;
    float a0 = alpha[(long)e*4 + 0], a1 = alpha[(long)e*4 + 1];
    float a2 = alpha[(long)e*4 + 2], a3 = alpha[(long)e*4 + 3];
    const BF16* ar = A + (long)s*Din;
    if (NJ == 8){
      short8 v = *(const short8*)(ar + lane*8);
      #pragma unroll
      for (int j = 0; j < NJ; ++j){
        float x = bf2f(v[j]);
        acc[0][j] += a0*x; acc[1][j] += a1*x; acc[2][j] += a2*x; acc[3][j] += a3*x;
      }
    } else {
      ushort2 v = *(const ushort2*)(ar + lane*2);
      float x0 = bf2f((short)v.x), x1 = bf2f((short)v.y);
      acc[0][0] += a0*x0; acc[1][0] += a1*x0; acc[2][0] += a2*x0; acc[3][0] += a3*x0;
      acc[0][1] += a0*x1; acc[1][1] += a1*x1; acc[2][1] += a2*x1; acc[3][1] += a3*x1;
    }
  }
  #pragma unroll
  for (int h = 0; h < 4; ++h){
    if (NJ == 8){
      short8 g;
      #pragma unroll
      for (int j = 0; j < NJ; ++j) g[j] = (short)f2bf(acc[h][j]);
      *(short8*)(G + ((long)wid*4 + h)*Din + lane*8) = g;
    } else {
      ushort2 g;
      g.x = f2bf(acc[h][0]); g.y = f2bf(acc[h][1]);
      *(ushort2*)(G + ((long)wid*4 + h)*Din + lane*2) = g;
    }
  }
}

// ---------------- aggregation body (vectorized ushort2 for NJ==2) ---------
template<int NJ>
__device__ __forceinline__ void agg_body(
    const BF16* __restrict__ Zt, const float* __restrict__ alpha,
    const int* __restrict__ indptr, const int* __restrict__ esrc,
    float* acc, int wid, int lane, int TW, int head0, int E, int ns)
{
  int e0 = indptr[wid], e1 = indptr[wid+1];
  e0 = max(0, min(e0, E)); e1 = max(e0, min(e1, E));
  for (int e = e0; e < e1; ++e){
    int s = esrc[e]; if ((unsigned)s >= (unsigned)ns) s = 0;
    float aA = alpha[(long)e*4 + head0];
    const BF16* zr = Zt + (long)s*TW;
    if (NJ == 2){
      ushort2 z = *(const ushort2*)(zr + lane*2);
      acc[0] += aA * bf2f((short)z.x);
      acc[1] += aA * bf2f((short)z.y);
    } else {
      acc[0] += aA * ldE(zr, lane);
    }
  }
}

// ---------------- fused 2-relation aggregation (phase 1, dst=acc) ---------
template<int NJ>
__global__ __launch_bounds__(256) void k_agg2(
    const BF16* __restrict__ Z0, const BF16* __restrict__ Z1,
    const float* __restrict__ a0, const float* __restrict__ a1,
    const int* __restrict__ ip0, const int* __restrict__ ip1,
    const int* __restrict__ es0, const int* __restrict__ es1,
    BF16* __restrict__ out, int ldc, int c0w, int TW, int head0,
    int n_dst, int E, int ns0, int ns1)
{
  int wid = (blockIdx.x*blockDim.x + threadIdx.x) >> 6;
  int lane = threadIdx.x & 63;
  if (wid >= n_dst) return;
  float acc[NJ];
  #pragma unroll
  for (int j = 0; j < NJ; ++j) acc[j] = 0.f;
  agg_body<NJ>(Z0, a0, ip0, es0, acc, wid, lane, TW, head0, E, ns0);
  agg_body<NJ>(Z1, a1, ip1, es1, acc, wid, lane, TW, head0, E, ns1);
  if (NJ == 2){
    ushort2 g; g.x = f2bf(acc[0]); g.y = f2bf(acc[1]);
    *(ushort2*)(out + (long)wid*ldc + c0w + lane*2) = g;
  } else {
    stE(out, (long)wid*ldc + c0w + lane, acc[0]);
  }
}

// ---------------- fused 3-relation aggregation (phase 2, dst=tx) ----------
template<int NJ>
__global__ __launch_bounds__(256) void k_agg3(
    const BF16* __restrict__ Z0, const BF16* __restrict__ Z1, const BF16* __restrict__ Z2,
    const float* __restrict__ a0, const float* __restrict__ a1, const float* __restrict__ a2,
    const int* __restrict__ ip0, const int* __restrict__ ip1, const int* __restrict__ ip2,
    const int* __restrict__ es0, const int* __restrict__ es1, const int* __restrict__ es2,
    BF16* __restrict__ out, int ldc, int TW, int head0,
    int n_dst, int E, int ns0, int ns1, int ns2)
{
  int wid = (blockIdx.x*blockDim.x + threadIdx.x) >> 6;
  int lane = threadIdx.x & 63;
  if (wid >= n_dst) return;
  float acc[NJ];
  #pragma unroll
  for (int j = 0; j < NJ; ++j) acc[j] = 0.f;
  agg_body<NJ>(Z0, a0, ip0, es0, acc, wid, lane, TW, head0, E, ns0);
  agg_body<NJ>(Z1, a1, ip1, es1, acc, wid, lane, TW, head0, E, ns1);
  agg_body<NJ>(Z2, a2, ip2, es2, acc, wid, lane, TW, head0, E, ns2);
  if (NJ == 2){
    ushort2 g; g.x = f2bf(acc[0]); g.y = f2bf(acc[1]);
    *(ushort2*)(out + (long)wid*ldc + lane*2) = g;
  } else {
    stE(out, (long)wid*ldc + lane, acc[0]);
  }
}

// ---------------- BN stats over nw_tile [N, TW] bf16 ----------------------
__global__ void k_bnp(const BF16* __restrict__ nw, float* __restrict__ bnp,
                      int N, int TW, int P)
{
  int col  = threadIdx.x & (TW - 1);
  int slot = threadIdx.x / TW;
  int rpb  = 256 / TW;
  int p    = blockIdx.x*rpb + slot;
  float s = 0.f, s2 = 0.f;
  for (long r = p; r < N; r += P){
    float v = ldE(nw, r*TW + col);
    s += v; s2 += v*v;
  }
  bnp[(long)p*2*TW + col]      = s;
  bnp[(long)p*2*TW + TW + col] = s2;
}
__global__ void k_bnf(const float* __restrict__ bnp, float* __restrict__ bns,
                      int P, int TW)
{
  int c = blockIdx.x*256 + threadIdx.x;
  if (c >= 2*TW) return;
  float s = 0.f;
  for (int p = 0; p < P; ++p) s += bnp[(long)p*2*TW + c];
  bns[c] = s;
}
// ---------------- BN apply (short8, 8 elems/thread) -----------------------
__global__ void k_bn_apply(const BF16* __restrict__ nw, const float* __restrict__ bns,
                           const float* __restrict__ g, const float* __restrict__ b,
                           BF16* __restrict__ A, int N, int TW, int c0, int res)
{
  long total8 = (long)N*TW/8;
  for (long i8 = (long)blockIdx.x*blockDim.x + threadIdx.x; i8 < total8;
       i8 += (long)gridDim.x*blockDim.x){
    long i = i8*8;
    int col = (int)(i % TW);
    long r  = i / TW;
    short8 nv = *(const short8*)(nw + i);
    long ai = r*512 + c0 + col;
    short8 av;
    if (res) av = *(const short8*)(A + ai);
    short8 ov;
    #pragma unroll
    for (int k = 0; k < 8; ++k){
      int gc = c0 + col + k;
      float mu  = bns[col+k] / (float)N;
      float var = bns[TW + col + k] / (float)N - mu*mu;
      float sc = g[gc] * rsqrtf(var + 1e-5f);
      float sh = b[gc] - mu*sc;
      float v = fmaxf(bf2f(nv[k])*sc + sh, 0.f);
      if (res) v += bf2f(av[k]);
      ov[k] = (short)f2bf(v);
    }
    *(short8*)(A + ai) = ov;
  }
}

// ---------------- acc/mer update (short8) ----------------
__global__ void k_update(const BF16* __restrict__ B, const float* __restrict__ ab1,
                         const float* __restrict__ ab2, BF16* __restrict__ A,
                         long n512, int res)
{
  long n8 = n512/8;
  for (long i8 = (long)blockIdx.x*blockDim.x + threadIdx.x; i8 < n8;
       i8 += (long)gridDim.x*blockDim.x){
    long i = i8*8;
    int c = (int)(i & 511);
    short8 bv = *(const short8*)(B + i);
    short8 av;
    if (res) av = *(const short8*)(A + i);
    short8 ov;
    #pragma unroll
    for (int k = 0; k < 8; ++k){
      float v = bf2f(bv[k]) + ab1[c+k] + (ab2 ? ab2[c+k] : 0.f);
      v = fmaxf(v, 0.f);
      if (res) v += bf2f(av[k]);
      ov[k] = (short)f2bf(v);
    }
    *(short8*)(A + i) = ov;
  }
}

// ---------------- head logits ----------------
__global__ void k_logits(const BF16* __restrict__ Hid, const float* __restrict__ Wh2,
                         const float* __restrict__ bh2, float* __restrict__ out, int N)
{
  int node = (blockIdx.x*blockDim.x + threadIdx.x) >> 6;
  int lane = threadIdx.x & 63;
  if (node >= N) return;
  float v = ldE(Hid, (long)node*64 + lane) * Wh2[lane];
  #pragma unroll
  for (int off = 32; off; off >>= 1) v += __shfl_down(v, off, 64);
  if (lane == 0) out[node] = v + bh2[0];
}

// ---------------------------------------------------------------------------
struct Arena {
  BF16 *A[3];
  BF16 *Bst[3];
  BF16 *Zt;
  BF16 *blkB;
  BF16 *hidden;
  float *scoreS, *scoreD;
  float *alpha;
  float *Fbuf;
  float *bnp, *bns;
  int *counts, *bsums;
  int *indptr[6], *esrc[6];
  BF16 *Wt0[6], *WtL[2][6], *Wh1t;
  size_t total;
};

extern "C" void kernel_launch(void* const* d_in, const int* in_sizes, int n_in,
                              void* d_out, int out_size, void* d_ws, size_t ws_size,
                              hipStream_t stream)
{
  const float* x_tx  = (const float*)d_in[0];
  const float* x_acc = (const float*)d_in[1];
  const float* x_mer = (const float*)d_in[2];
  const float* Wtx = (const float*)d_in[3];  const float* btx  = (const float*)d_in[4];
  const float* Wacc= (const float*)d_in[5];  const float* bacc = (const float*)d_in[6];
  const float* Wmer= (const float*)d_in[7];  const float* bmer = (const float*)d_in[8];
  const float* W0   = (const float*)d_in[9];
  const float* Wrest= (const float*)d_in[10];
  const float* att_s= (const float*)d_in[11];
  const float* att_d= (const float*)d_in[12];
  const float* att_b= (const float*)d_in[13];
  const float* bn_g = (const float*)d_in[14];
  const float* bn_b = (const float*)d_in[15];
  const float* Wh1  = (const float*)d_in[16]; const float* bh1 = (const float*)d_in[17];
  const float* Wh2  = (const float*)d_in[18]; const float* bh2 = (const float*)d_in[19];
  const int*   edges= (const int*)d_in[20];

  const int E    = in_sizes[20] / 12;
  const int nTx  = in_sizes[0] / 64;
  const int nAcc = in_sizes[1] / 32;
  const int nMer = in_sizes[2] / 32;
  const int nOf[3]   = {nTx, nAcc, nMer};
  const int SRC_T[6] = {0,0,0,1,1,2};
  const int DST_T[6] = {1,1,2,0,0,0};
  const int maxN = max(nTx, max(nAcc, nMer));
  (void)n_in;

  auto layout = [&](int TW)->Arena{
    Arena P{};
    size_t off = 0;
    auto a = [&](size_t bytes)->char*{
      char* p = (char*)d_ws + off;
      off += (bytes + 255) & ~(size_t)255;
      return p;
    };
    auto al = [](size_t b){ return (b + 255) & ~(size_t)255; };
    P.A[0]   = (BF16*)a((size_t)nTx *512*2);
    P.A[1]   = (BF16*)a((size_t)nAcc*512*2);
    P.A[2]   = (BF16*)a((size_t)nMer*512*2);
    P.Bst[1] = (BF16*)a((size_t)nAcc*512*2);
    P.Bst[2] = (BF16*)a((size_t)nMer*512*2);
    size_t zrowsA = (size_t)maxN > (size_t)2*nAcc + nMer ? (size_t)maxN : (size_t)2*nAcc + nMer;
    size_t blkA = al(zrowsA*TW*2);
    size_t blkBsz = al((size_t)nTx*TW*2);
    size_t gB = al((size_t)nMer*4*512*2);
    if (gB > blkBsz) blkBsz = gB;
    size_t scoreB = al((size_t)3*maxN*4*4)*2;
    size_t hidB = al((size_t)nTx*64*2);
    size_t scr = blkA + blkBsz;
    if (scr < scoreB) scr = scoreB;
    if (scr < hidB)   scr = hidB;
    char* scrBase = a(scr);
    P.Zt     = (BF16*)scrBase;
    P.blkB   = (BF16*)(scrBase + blkA);
    P.scoreS = (float*)scrBase;
    P.scoreD = (float*)(scrBase + al((size_t)3*maxN*4*4));
    P.hidden = (BF16*)scrBase;
    P.alpha  = (float*)a((size_t)3*E*4*4);
    P.Fbuf   = (float*)a((size_t)6*8*512*4);
    P.bnp    = (float*)a(262144);
    P.bns    = (float*)a(4096);
    P.counts = (int*)a((size_t)maxN*4);
    P.bsums  = (int*)a(4096);
    for (int r = 0; r < 6; ++r){
      P.indptr[r] = (int*)a((size_t)(nOf[DST_T[r]]+1)*4);
      P.esrc[r]   = (int*)a((size_t)E*4);
    }
    for (int r = 0; r < 6; ++r) P.Wt0[r] = (BF16*)a((size_t)512*128*2);
    for (int l = 0; l < 2; ++l)
      for (int r = 0; r < 6; ++r) P.WtL[l][r] = (BF16*)a((size_t)512*512*2);
    P.Wh1t = (BF16*)a((size_t)64*512*2);
    P.total = off;
    return P;
  };

  int TW = 0;
  Arena P{};
  for (int cand : {128, 64}){
    P = layout(cand);
    if (P.total <= ws_size){ TW = cand; break; }
  }
  if (TW == 0){
    float sentinel = 10000.0f + (float)(ws_size >> 20);
    k_fill_f32<<<dim3((out_size+255)/256), dim3(256), 0, stream>>>((float*)d_out, (long)out_size, sentinel);
    return;
  }
  const int nTiles = 512 / TW;
  const int NJv = TW/64;
  const int rpb = 256 / TW, PBX = 64, Pp = PBX * rpb;
  dim3 b256(256);

  // ---- 0. weight prep (3 batched launches) ----
  k_wt<<<dim3(16,4,6),  b256, 0, stream>>>(W0,    P.Wt0[0],    128, 512);
  k_wt<<<dim3(16,16,12),b256, 0, stream>>>(Wrest, P.WtL[0][0], 512, 512);
  k_wt<<<dim3(2,16,1),  b256, 0, stream>>>(Wh1,   P.Wh1t,      512, 64);

  auto mfma_gemm = [&](const BF16* A, const BF16* Bt, BF16* Cp, int M, int K, int c0, int ldc){
    if (TW >= 128)
      k_mfma<128,2,2,4,4,BF16><<<dim3(TW/128,(M+127)/128,1),b256,0,stream>>>(
          A, Bt, Cp, M, K, c0, ldc, K, (const float*)nullptr, 0, 0, 0L, 0L, 0, (const BF16*)nullptr);
    else
      k_mfma<64,4,1,2,4,BF16><<<dim3(1,(M+127)/128,1),b256,0,stream>>>(
          A, Bt, Cp, M, K, c0, ldc, K, (const float*)nullptr, 0, 0, 0L, 0L, 0, (const BF16*)nullptr);
  };
  // pair GEMM: one 512-thread block computes BOTH weight matrices' 128-col
  // outputs, staging the A tile once (k_mfma2).
  auto mfma_pair = [&](const BF16* A, const BF16* Bt0, const BF16* Bt1p, BF16* Cp, long cZst,
                       int M, int K, int c0){
    if (TW >= 128)
      k_mfma2<<<dim3(1,(M+127)/128,1), dim3(512), 0, stream>>>(
          A, Bt0, Bt1p, Cp, Cp + cZst, M, K, c0, TW, K);
    else {
      mfma_gemm(A, Bt0, Cp, M, K, c0, TW);
      mfma_gemm(A, Bt1p, Cp + cZst, M, K, c0, TW);
    }
  };

  // ---- 1. CSR build (per-relation) ----
  for (int r = 0; r < 6; ++r){
    int nd = nOf[DST_T[r]], ns = nOf[SRC_T[r]];
    const int* srcP = edges + (size_t)r*2*E;
    const int* dstP = srcP + E;
    int nb = (nd + 255)/256;
    k_zero   <<<dim3(nb),          b256, 0, stream>>>(P.counts, (long)nd);
    k_hist   <<<dim3((E+255)/256), b256, 0, stream>>>(dstP, P.counts, E, nd);
    k_scan1  <<<dim3(nb),          b256, 0, stream>>>(P.counts, P.indptr[r], P.bsums, nd);
    k_scan2  <<<dim3(1),           dim3(1024),0, stream>>>(P.bsums, nb);
    k_scan3  <<<dim3(nb),          b256, 0, stream>>>(P.indptr[r], P.bsums, nd);
    k_zero   <<<dim3(nb),          b256, 0, stream>>>(P.counts, (long)nd);
    k_scatter<<<dim3((E+255)/256), b256, 0, stream>>>(srcP, dstP, P.indptr[r], P.counts, P.esrc[r], E, nd, ns);
  }

  // ---- 2. encoders ----
  k_gemm<float,BF16><<<dim3(2,(nTx +63)/64), b256, 0, stream>>>(x_tx,  Wtx,  P.A[0], nTx,  128, 64, 128, btx,  1);
  k_gemm<float,BF16><<<dim3(2,(nAcc+63)/64), b256, 0, stream>>>(x_acc, Wacc, P.A[1], nAcc, 128, 32, 128, bacc, 1);
  k_gemm<float,BF16><<<dim3(2,(nMer+63)/64), b256, 0, stream>>>(x_mer, Wmer, P.A[2], nMer, 128, 32, 128, bmer, 1);

  const long mS = (long)maxN*4;
  // ---- 3. layers ----
  for (int i = 0; i < 3; ++i){
    const int Din = (i == 0) ? 128 : 512;
    const int res = (i > 0) ? 1 : 0;
    const long fstr = 8L*Din;
    const float* WbaseL = (i == 0) ? W0 : (Wrest + (size_t)(i-1)*6*512*512);
    const long wstride = (i == 0) ? 128L*512 : 512L*512;
    auto Wtof = [&](int r)->const BF16*{ return (i == 0) ? P.Wt0[r] : P.WtL[i-1][r]; };

    k_foldAll<<<dim3(48*Din/4), b256, 0, stream>>>(WbaseL, wstride,
        att_s + (size_t)i*6*512, att_d + (size_t)i*6*512, P.Fbuf, Din);

    // ---- Phase 1: scores, then ALL alphas (batched) ----
    k_scoreM<3><<<dim3((nTx+15)/16), b256, 0, stream>>>(P.A[0], P.Fbuf,           fstr, P.scoreS, mS, nTx, Din);
    k_scoreM<2><<<dim3((nAcc+15)/16), b256, 0, stream>>>(P.A[1], P.Fbuf + 4*Din,  fstr, P.scoreD, mS, nAcc, Din);
    k_scoreM<1><<<dim3((nMer+15)/16), b256, 0, stream>>>(P.A[2], P.Fbuf + 20*Din, fstr, P.scoreD + 2*mS, 0, nMer, Din);
    {
      AlphaArgs aa{};
      int ndMax = 0;
      for (int r = 0; r < 3; ++r){
        aa.ss[r] = P.scoreS + r*mS; aa.sd[r] = P.scoreD + r*mS;
        aa.ip[r] = P.indptr[r]; aa.es[r] = P.esrc[r];
        aa.al[r] = P.alpha + (size_t)r*E*4;
        aa.nd[r] = nOf[DST_T[r]]; aa.ns[r] = nTx;
        if (aa.nd[r] > ndMax) ndMax = aa.nd[r];
      }
      k_alpha3b<<<dim3((ndMax+3)/4,3), b256, 0, stream>>>(aa, E);
    }
    // r=2 (tx->mer): aggregate-FIRST; 4 head-GEMMs in one z=4 launch
    {
      BF16* Gm = P.blkB;
      if (Din == 512)
        k_gather4<8><<<dim3((nMer+3)/4), b256, 0, stream>>>(P.A[0], P.alpha + (size_t)2*E*4,
            P.indptr[2], P.esrc[2], Gm, nMer, Din, E, nTx);
      else
        k_gather4<2><<<dim3((nMer+3)/4), b256, 0, stream>>>(P.A[0], P.alpha + (size_t)2*E*4,
            P.indptr[2], P.esrc[2], Gm, nMer, Din, E, nTx);
      k_mfma<128,2,2,4,4,BF16><<<dim3(1,(nMer+127)/128,4), b256, 0, stream>>>(
          Gm, Wtof(2), P.Bst[2], nMer, Din, 0, 512, 4*Din,
          (const float*)nullptr, 0, 0, (long)Din, 128L, 128, (const BF16*)nullptr);
    }
    // r=0,1 (tx->acc): fused-pair GEMM (A staged once) + fused agg2
    {
      BF16* Zr0 = P.Zt;
      BF16* Zr1 = P.blkB;
      long zst = (long)(Zr1 - Zr0);
      for (int t = 0; t < nTiles; ++t){
        int c0 = t*TW;
        mfma_pair(P.A[0], Wtof(0), Wtof(1), Zr0, zst, nTx, Din, c0);
        dim3 ga((nAcc+3)/4);
        if (NJv == 2)
          k_agg2<2><<<ga,b256,0,stream>>>(Zr0, Zr1, P.alpha, P.alpha + (size_t)E*4,
              P.indptr[0], P.indptr[1], P.esrc[0], P.esrc[1],
              P.Bst[1], 512, c0, TW, c0>>7, nAcc, E, nTx, nTx);
        else
          k_agg2<1><<<ga,b256,0,stream>>>(Zr0, Zr1, P.alpha, P.alpha + (size_t)E*4,
              P.indptr[0], P.indptr[1], P.esrc[0], P.esrc[1],
              P.Bst[1], 512, c0, TW, c0>>7, nAcc, E, nTx, nTx);
      }
    }

    // ---- Phase 2 (dst=tx; src=acc r=3,4; mer r=5) ----
    k_scoreM<2><<<dim3((nAcc+15)/16), b256, 0, stream>>>(P.A[1], P.Fbuf + 24*Din, fstr, P.scoreS, mS, nAcc, Din);
    k_scoreM<1><<<dim3((nMer+15)/16), b256, 0, stream>>>(P.A[2], P.Fbuf + 40*Din, fstr, P.scoreS + 2*mS, 0, nMer, Din);
    k_scoreM<3><<<dim3((nTx+15)/16), b256, 0, stream>>>(P.A[0], P.Fbuf + 28*Din, fstr, P.scoreD, mS, nTx, Din);
    {
      AlphaArgs aa{};
      for (int q = 0; q < 3; ++q){
        int r = 3 + q;
        aa.ss[q] = P.scoreS + q*mS; aa.sd[q] = P.scoreD + q*mS;
        aa.ip[q] = P.indptr[r]; aa.es[q] = P.esrc[r];
        aa.al[q] = P.alpha + (size_t)q*E*4;
        aa.nd[q] = nTx; aa.ns[q] = nOf[SRC_T[r]];
      }
      k_alpha3b<<<dim3((nTx+3)/4,3), b256, 0, stream>>>(aa, E);
    }
    BF16* Z3 = P.Zt;
    BF16* Z4 = P.Zt + (size_t)nAcc*TW;
    BF16* Z5 = P.Zt + (size_t)2*nAcc*TW;
    BF16* nw = P.blkB;
    for (int t = 0; t < nTiles; ++t){
      int c0 = t*TW;
      mfma_pair(P.A[1], Wtof(3), Wtof(4), Z3, (long)nAcc*TW, nAcc, Din, c0);
      mfma_gemm(P.A[2], Wtof(5), Z5, nMer, Din, c0, TW);
      dim3 ga((nTx+3)/4);
      if (NJv == 2)
        k_agg3<2><<<ga,b256,0,stream>>>(Z3,Z4,Z5, P.alpha, P.alpha+(size_t)E*4, P.alpha+(size_t)2*E*4,
            P.indptr[3],P.indptr[4],P.indptr[5], P.esrc[3],P.esrc[4],P.esrc[5],
            nw, TW, TW, c0>>7, nTx, E, nAcc, nAcc, nMer);
      else
        k_agg3<1><<<ga,b256,0,stream>>>(Z3,Z4,Z5, P.alpha, P.alpha+(size_t)E*4, P.alpha+(size_t)2*E*4,
            P.indptr[3],P.indptr[4],P.indptr[5], P.esrc[3],P.esrc[4],P.esrc[5],
            nw, TW, TW, c0>>7, nTx, E, nAcc, nAcc, nMer);
      k_bnp<<<dim3(PBX), b256, 0, stream>>>(nw, P.bnp, nTx, TW, Pp);
      k_bnf<<<dim3((2*TW+255)/256), b256, 0, stream>>>(P.bnp, P.bns, Pp, TW);
      k_bn_apply<<<dim3(2048), b256, 0, stream>>>(nw, P.bns,
          bn_g + (size_t)i*512, bn_b + (size_t)i*512, P.A[0], nTx, TW, c0, res);
    }
    // ---- Phase 3 ----
    const float* ab0 = att_b + ((size_t)(i*6 + 0))*512;
    const float* ab1 = att_b + ((size_t)(i*6 + 1))*512;
    const float* ab2 = att_b + ((size_t)(i*6 + 2))*512;
    k_update<<<dim3(1024), b256, 0, stream>>>(P.Bst[1], ab0, ab1, P.A[1], (long)nAcc*512, res);
    k_update<<<dim3(128),  b256, 0, stream>>>(P.Bst[2], ab2, (const float*)nullptr, P.A[2], (long)nMer*512, res);
  }

  // ---- 4. head ----
  k_mfma<64,4,1,2,4,BF16><<<dim3(1,(nTx+127)/128,1), b256, 0, stream>>>(
      P.A[0], P.Wh1t, P.hidden, nTx, 512, 0, 64, 512, bh1, 1, 0,
      0L, 0L, 0, (const BF16*)nullptr);
  k_logits<<<dim3((nTx+3)/4), b256, 0, stream>>>(P.hidden, Wh2, bh2, (float*)d_out, nTx);
}